// Round 1
// baseline (732.680 us; speedup 1.0000x reference)
//
#include <hip/hip_runtime.h>
#include <stdint.h>
#include <stddef.h>

// ---------------- problem constants ----------------
#define S_LEN 2048
#define HIDN  2048
#define HQ    16
#define HKV   4
#define HDIM  128
#define NQKV  3072      // HQ*D + 2*HKV*D
#define QBLK  32        // S/64
#define GHW   128
#define INTER 5632
#define NEGF  (-1e30f)
#define THRG  0.004f

typedef short bf16x8 __attribute__((ext_vector_type(8)));
typedef float f32x4  __attribute__((ext_vector_type(4)));

__device__ __forceinline__ short f2bf(float f) {
  union { float f; unsigned u; } v; v.f = f;
  unsigned r = (v.u + 0x7FFFu + ((v.u >> 16) & 1u)) >> 16;
  return (short)r;
}
__device__ __forceinline__ float bf2f(short s) {
  union { float f; unsigned u; } v; v.u = ((unsigned)(unsigned short)s) << 16;
  return v.f;
}
__device__ __forceinline__ void gload16(const void* g, void* l) {
  __builtin_amdgcn_global_load_lds(
      (const __attribute__((address_space(1))) void*)g,
      (__attribute__((address_space(3))) void*)l, 16, 0, 0);
}
// pack two f32 -> [bf16(hi)<<16 | bf16(lo)] via byte-select (truncation)
__device__ __forceinline__ unsigned pack_bf2(float hi, float lo) {
  return __builtin_amdgcn_perm(__float_as_uint(hi), __float_as_uint(lo), 0x07060302u);
}

// ---------------- transpose + cast fp32 (R x C) -> bf16 (C x R) ----------------
__global__ __launch_bounds__(256) void k_transpose_cast(
    const float* __restrict__ src, short* __restrict__ dst, int R, int C) {
  __shared__ float t[32][33];
  const int tx = threadIdx.x, ty = threadIdx.y;
  const int x = blockIdx.x * 32 + tx;
  const int y0 = blockIdx.y * 32;
#pragma unroll
  for (int i = 0; i < 4; i++) {
    int yy = ty + i * 8;
    t[yy][tx] = src[(long)(y0 + yy) * C + x];
  }
  __syncthreads();
  const int xo = blockIdx.y * 32 + tx;
  const int yo0 = blockIdx.x * 32;
#pragma unroll
  for (int i = 0; i < 4; i++) {
    int yy = ty + i * 8;
    dst[(long)(yo0 + yy) * R + xo] = f2bf(t[tx][yy]);
  }
}

// ---------------- concat qkv bias ----------------
__global__ void k_bias_concat(const float* __restrict__ bq, const float* __restrict__ bk,
                              const float* __restrict__ bv, float* __restrict__ out) {
  int i = blockIdx.x * 256 + threadIdx.x;
  if (i < 2048) out[i] = bq[i];
  else if (i < 2560) out[i] = bk[i - 2048];
  else out[i] = bv[i - 2560];
}

// ---------------- RMSNorm fp32 -> bf16 ----------------
__global__ __launch_bounds__(256) void k_rms(const float* __restrict__ x,
                                             const float* __restrict__ w,
                                             short* __restrict__ out) {
  const int row = blockIdx.x;
  const float* xr = x + (long)row * HIDN;
  float v[8];
  float ss = 0.f;
#pragma unroll
  for (int i = 0; i < 8; i++) {
    v[i] = xr[threadIdx.x + i * 256];
    ss += v[i] * v[i];
  }
#pragma unroll
  for (int off = 32; off > 0; off >>= 1) ss += __shfl_down(ss, off, 64);
  __shared__ float red[4];
  const int wave = threadIdx.x >> 6, lane = threadIdx.x & 63;
  if (lane == 0) red[wave] = ss;
  __syncthreads();
  float tot = red[0] + red[1] + red[2] + red[3];
  float rs = rsqrtf(tot / (float)HIDN + 1e-6f);
#pragma unroll
  for (int i = 0; i < 8; i++) {
    int c = threadIdx.x + i * 256;
    out[(long)row * HIDN + c] = f2bf(v[i] * rs * w[c]);
  }
}

// ---------------- GEMM: C[M,N] = A[M,K](bf16) * Bt[N,K](bf16)^T  ----------------
// MODE 0: Cf = acc + bias? + add?   (fp32 out)
// MODE 1: Cb = bf16(acc)
// MODE 2: Cb = bf16(silu(gaux) * acc)
// BN in {64,128}. BK=64: tiles stored as two k-half panels [2][rows][32]
// (64B rows -> 2-way/free LDS reads), halving barrier count vs BK=32.
template <int MODE, int BN>
__global__ __launch_bounds__(256) void k_gemm(
    const short* __restrict__ A, const short* __restrict__ Bt,
    float* __restrict__ Cf, short* __restrict__ Cb,
    const float* __restrict__ bias, const float* __restrict__ add,
    const short* __restrict__ gaux, int M, int N, int K) {
  constexpr int NT = BN / 32;   // n-tiles per wave
  constexpr int BIW = BN / 32;  // per-wave B staging instrs
  constexpr int BPP = BN / 16;  // B staging instrs per k-half panel
  __shared__ short As[2][128][32];
  __shared__ short Bs[2][BN][32];
  const int tid = threadIdx.x;
  const int wave = tid >> 6, lane = tid & 63, quad = lane >> 4, l15 = lane & 15;
  const long m0 = (long)blockIdx.y * 128, n0 = (long)blockIdx.x * BN;
  const int wr = (wave >> 1) * 64, wc = (wave & 1) * (BN / 2);
  const int i2 = lane >> 2, i3 = lane & 3;
  f32x4 acc[4][NT] = {};
  // A staging: 16 instrs (4/wave). instr g: k-half h=g>>3, rows (g&7)*16..+15
  const short* Ainst[4];
  short* Alds[4];
#pragma unroll
  for (int j = 0; j < 4; j++) {
    const int g = wave * 4 + j, h = g >> 3, rb = (g & 7) * 16;
    Ainst[j] = A + (m0 + rb + i2) * K + h * 32 + i3 * 8;
    Alds[j] = &As[h][rb][0];
  }
  // B staging: BN/8 instrs (BIW/wave)
  const short* Binst[BIW];
  short* Blds[BIW];
#pragma unroll
  for (int j = 0; j < BIW; j++) {
    const int g = wave * BIW + j, h = g / BPP, rb = (g % BPP) * 16;
    Binst[j] = Bt + (n0 + rb + i2) * K + h * 32 + i3 * 8;
    Blds[j] = &Bs[h][rb][0];
  }
  for (int k0 = 0; k0 < K; k0 += 64) {
    __syncthreads();
#pragma unroll
    for (int j = 0; j < 4; j++) gload16(Ainst[j] + k0, Alds[j]);
#pragma unroll
    for (int j = 0; j < BIW; j++) gload16(Binst[j] + k0, Blds[j]);
    __syncthreads();
#pragma unroll
    for (int s = 0; s < 2; s++) {
      bf16x8 af[4], bb[NT];
#pragma unroll
      for (int mi = 0; mi < 4; mi++)
        af[mi] = *(const bf16x8*)&As[s][wr + mi * 16 + l15][quad * 8];
#pragma unroll
      for (int ni = 0; ni < NT; ni++)
        bb[ni] = *(const bf16x8*)&Bs[s][wc + ni * 16 + l15][quad * 8];
#pragma unroll
      for (int mi = 0; mi < 4; mi++)
#pragma unroll
        for (int ni = 0; ni < NT; ni++)
          acc[mi][ni] = __builtin_amdgcn_mfma_f32_16x16x32_bf16(af[mi], bb[ni], acc[mi][ni], 0, 0, 0);
    }
  }
  const bool hb = (MODE == 0) && (bias != nullptr);
  const bool ha = (MODE == 0) && (add != nullptr);
#pragma unroll
  for (int mi = 0; mi < 4; mi++) {
#pragma unroll
    for (int ni = 0; ni < NT; ni++) {
      long mbase = m0 + wr + mi * 16 + quad * 4;
      long n = n0 + wc + ni * 16 + l15;
#pragma unroll
      for (int r = 0; r < 4; r++) {
        float v = acc[mi][ni][r];
        long idx = (mbase + r) * N + n;
        if (MODE == 0) {
          if (hb) v += bias[n];
          if (ha) v += add[idx];
          Cf[idx] = v;
        } else if (MODE == 1) {
          Cb[idx] = f2bf(v);
        } else {
          float g = bf2f(gaux[idx]);
          float sg = g / (1.f + __expf(-g));
          Cb[idx] = f2bf(sg * v);
        }
      }
    }
  }
}

// ---------------- block means of q and k (pre-RoPE) ----------------
__global__ __launch_bounds__(256) void k_blockmean(const float* __restrict__ qkv,
                                                   float* __restrict__ qm,
                                                   float* __restrict__ km) {
  int id = blockIdx.x * 256 + threadIdx.x;  // 32 * 2560
  int qb = id / 2560, c = id % 2560;        // cols 0..2559 = q(2048) + k(512)
  const float* base = qkv + (long)qb * 64 * NQKV + c;
  float acc = 0.f;
  for (int s = 0; s < 64; s++) acc += base[(long)s * NQKV];
  acc *= (1.f / 64.f);
  if (c < 2048) qm[(long)qb * 2048 + c] = acc;
  else km[(long)qb * 512 + (c - 2048)] = acc;
}

// ---------------- gate projections qg = qm@gWq, kg = km@gWk ----------------
__global__ __launch_bounds__(128) void k_gateproj(const float* __restrict__ qm,
                                                  const float* __restrict__ km,
                                                  const float* __restrict__ gWq,
                                                  const float* __restrict__ gWk,
                                                  float* __restrict__ qg,
                                                  float* __restrict__ kg) {
  __shared__ float xm[128];
  const int b = blockIdx.x;
  const float* src; const float* W; float* dst;
  if (b < 512) { src = qm + (long)b * 128; W = gWq; dst = qg + (long)b * 128; }
  else { int r = b - 512; src = km + (long)r * 128; W = gWk; dst = kg + (long)r * 128; }
  xm[threadIdx.x] = src[threadIdx.x];
  __syncthreads();
  float acc = 0.f;
  for (int d = 0; d < 128; d++) acc += xm[d] * W[d * GHW + threadIdx.x];
  dst[threadIdx.x] = acc;
}

// ---------------- gate softmax + keep mask ----------------
__global__ __launch_bounds__(64) void k_gatemask(const float* __restrict__ qg,
                                                 const float* __restrict__ kg,
                                                 unsigned char* __restrict__ mask) {
  const int qb = blockIdx.x, h = blockIdx.y;
  __shared__ float qv[128];
  const int t = threadIdx.x;
  qv[t] = qg[((long)qb * 16 + h) * 128 + t];
  qv[t + 64] = qg[((long)qb * 16 + h) * 128 + t + 64];
  __syncthreads();
  const int kb = t;
  float s = NEGF;
  if (kb < 32 && kb <= qb) {
    const float* kr = kg + ((long)kb * 4 + (h >> 2)) * 128;
    float acc = 0.f;
    for (int d = 0; d < 128; d++) acc += qv[d] * kr[d];
    s = acc * 0.08838834764831845f;  // GH^-0.5
  }
  float m = s;
#pragma unroll
  for (int off = 32; off > 0; off >>= 1) m = fmaxf(m, __shfl_xor(m, off, 64));
  float e = (kb < 32 && kb <= qb) ? __expf(s - m) : 0.f;
  float sum = e;
#pragma unroll
  for (int off = 32; off > 0; off >>= 1) sum += __shfl_xor(sum, off, 64);
  if (kb < 32) {
    float gate = e / sum;
    bool keep = (kb <= qb) && (gate >= THRG || kb == qb);
    mask[((long)h * 32 + qb) * 32 + kb] = keep ? 1 : 0;
  }
}

// ---------------- RoPE + cast q,k -> head-major bf16 ----------------
__global__ __launch_bounds__(256) void k_rope(const float* __restrict__ qkv,
                                              const float* __restrict__ cosb,
                                              const float* __restrict__ sinb,
                                              short* __restrict__ q_bf,
                                              short* __restrict__ k_bf) {
  long id = (long)blockIdx.x * 256 + threadIdx.x;  // S * 20 * 64
  int d = (int)(id & 63);
  long rest = id >> 6;
  int head = (int)(rest % 20);
  int s = (int)(rest / 20);
  const float c = cosb[(long)s * HDIM + d];
  const float sn = sinb[(long)s * HDIM + d];
  if (head < HQ) {
    const float* src = qkv + (long)s * NQKV + head * HDIM;
    float x1 = src[d], x2 = src[d + 64];
    short* dst = q_bf + ((long)head * S_LEN + s) * HDIM;
    dst[d] = f2bf(x1 * c - x2 * sn);
    dst[d + 64] = f2bf(x2 * c + x1 * sn);
  } else {
    int hk = head - HQ;
    const float* src = qkv + (long)s * NQKV + 2048 + hk * HDIM;
    float x1 = src[d], x2 = src[d + 64];
    short* dst = k_bf + ((long)hk * S_LEN + s) * HDIM;
    dst[d] = f2bf(x1 * c - x2 * sn);
    dst[d + 64] = f2bf(x2 * c + x1 * sn);
  }
}

// ---------------- v transpose-cast (tiled, coalesced): v_t[hk][d][s] ----------------
__global__ __launch_bounds__(256) void k_vcast_t(const float* __restrict__ qkv,
                                                 short* __restrict__ v_t) {
  __shared__ float t[32][33];
  const int hk = blockIdx.z;
  const int tx = threadIdx.x, ty = threadIdx.y;  // 32 x 8
  const int d0 = blockIdx.x * 32;                // within HDIM
  const int s0 = blockIdx.y * 32;                // within S
  const float* src = qkv + 2560 + (long)hk * HDIM;
#pragma unroll
  for (int i = 0; i < 4; i++) {
    int s = ty + i * 8;
    t[s][tx] = src[(long)(s0 + s) * NQKV + d0 + tx];
  }
  __syncthreads();
  short* dst = v_t + (long)hk * HDIM * S_LEN;
#pragma unroll
  for (int i = 0; i < 4; i++) {
    int d = ty + i * 8;
    dst[(long)(d0 + d) * S_LEN + s0 + tx] = f2bf(t[tx][d]);
  }
}

// ---------------- flash attention: LDS staging + S^T register softmax ----------------
__global__ __launch_bounds__(256) void k_attn(const short* __restrict__ q_bf,
                                              const short* __restrict__ k_bf,
                                              const short* __restrict__ v_t,
                                              const unsigned char* __restrict__ mask,
                                              short* __restrict__ o_bf) {
  const int qb = blockIdx.x, h = blockIdx.y;
  const int tid = threadIdx.x, wave = tid >> 6, lane = tid & 63;
  const int quad = lane >> 4, l15 = lane & 15;
  __shared__ short Ks[4 * 64 * 32];   // panel kd: [row r][32]
  __shared__ short Vs[2 * 128 * 32];  // panel ksb: [d][32]
  __shared__ short Ps[4][16 * 72];    // per-wave P, padded stride 72 shorts
  short* Pw = Ps[wave];
  const int hk = h >> 2;
  const unsigned char* mptr = mask + ((long)h * 32 + qb) * 32;
  const float SCL = 0.08838834764831845f * 1.4426950408889634f;  // D^-.5 * log2e
  const int qrow_g = qb * 64 + wave * 16 + l15;  // this lane's q-row

  // Q B-frags (n = q-row indexed by l15), resident all kernel
  bf16x8 bq[4];
  {
    const short* qrp = q_bf + ((long)h * S_LEN + qrow_g) * HDIM + quad * 8;
#pragma unroll
    for (int kd = 0; kd < 4; kd++) bq[kd] = *(const bf16x8*)(qrp + kd * 32);
  }

  const short* kh = k_bf + (long)hk * S_LEN * HDIM;
  const short* vh = v_t + (long)hk * HDIM * S_LEN;

  const int i2 = lane >> 2, i3 = lane & 3;
  int koff[4], voff[4];
  const int vp = wave >> 1, vhh = wave & 1;
#pragma unroll
  for (int inst = 0; inst < 4; inst++) {
    koff[inst] = (inst * 16 + i2) * HDIM + wave * 32 + i3 * 8;
    voff[inst] = (vhh * 64 + inst * 16 + i2) * S_LEN + vp * 32 + i3 * 8;
  }

  f32x4 accO[8] = {};
  float mrow = -3.0e38f, lrow = 0.f;

  for (int kb = 0; kb <= qb; kb++) {
    if (!mptr[kb]) continue;  // block-uniform
    __syncthreads();  // prior iter's LDS reads done before overwrite
    {
      const int kg = kb * 64 * HDIM;
      const int vg = kb * 64;
#pragma unroll
      for (int inst = 0; inst < 4; inst++) {
        gload16(kh + kg + koff[inst], &Ks[wave * 2048 + inst * 512]);
        gload16(vh + vg + voff[inst], &Vs[vp * 4096 + (vhh * 64 + inst * 16) * 32]);
      }
    }
    __syncthreads();  // all staging landed (compiler drains vmcnt)

    // ---- S^T: 4 subtiles; lane ends with 16 scores for its q-row ----
    f32x4 sv[4];
#pragma unroll
    for (int nt = 0; nt < 4; nt++) {
      f32x4 t = {};
#pragma unroll
      for (int kd = 0; kd < 4; kd++) {
        bf16x8 ka = *(const bf16x8*)&Ks[kd * 2048 + (nt * 16 + l15) * 32 + quad * 8];
        t = __builtin_amdgcn_mfma_f32_16x16x32_bf16(ka, bq[kd], t, 0, 0, 0);
      }
      sv[nt] = t;
    }
    // ---- scale + mask + row max ----
    float lmx = -__builtin_inff();
    if (kb < qb) {
#pragma unroll
      for (int nt = 0; nt < 4; nt++)
#pragma unroll
        for (int r = 0; r < 4; r++) {
          sv[nt][r] *= SCL;
          lmx = fmaxf(lmx, sv[nt][r]);
        }
    } else {  // diagonal block
#pragma unroll
      for (int nt = 0; nt < 4; nt++)
#pragma unroll
        for (int r = 0; r < 4; r++) {
          const int kcol = kb * 64 + nt * 16 + quad * 4 + r;
          sv[nt][r] = (kcol <= qrow_g) ? sv[nt][r] * SCL : -__builtin_inff();
          lmx = fmaxf(lmx, sv[nt][r]);
        }
    }
    lmx = fmaxf(lmx, __shfl_xor(lmx, 16, 64));
    lmx = fmaxf(lmx, __shfl_xor(lmx, 32, 64));
    const float mnew = fmaxf(mrow, lmx);
    const float alpha = __builtin_amdgcn_exp2f(mrow - mnew);
    mrow = mnew;
    // ---- exp2 + sum + packed P write (padded stride, b64) ----
    float psum = 0.f;
#pragma unroll
    for (int nt = 0; nt < 4; nt++) {
#pragma unroll
      for (int r = 0; r < 4; r++) {
        float p = __builtin_amdgcn_exp2f(sv[nt][r] - mnew);
        sv[nt][r] = p;
        psum += p;
      }
      uint2 u;
      u.x = pack_bf2(sv[nt][1], sv[nt][0]);
      u.y = pack_bf2(sv[nt][3], sv[nt][2]);
      *(uint2*)&Pw[l15 * 72 + nt * 16 + quad * 4] = u;
    }
    psum += __shfl_xor(psum, 16, 64);
    psum += __shfl_xor(psum, 32, 64);
    lrow = lrow * alpha + psum;
    // ---- rescale accO (alpha broadcast: lane j<16 holds row j's alpha) ----
    float al[4];
#pragma unroll
    for (int r = 0; r < 4; r++) al[r] = __shfl(alpha, quad * 4 + r, 64);
#pragma unroll
    for (int dt = 0; dt < 8; dt++)
#pragma unroll
      for (int r = 0; r < 4; r++) accO[dt][r] *= al[r];
    // drain this wave's P writes before fragment reads (per-wave buffer)
    asm volatile("s_waitcnt lgkmcnt(0)" ::: "memory");
    // ---- PV: P(16x64) @ V^T panels ----
    bf16x8 pf[2];
#pragma unroll
    for (int ksb = 0; ksb < 2; ksb++)
      pf[ksb] = *(const bf16x8*)&Pw[l15 * 72 + ksb * 32 + quad * 8];
#pragma unroll
    for (int dt = 0; dt < 8; dt++) {
#pragma unroll
      for (int ksb = 0; ksb < 2; ksb++) {
        bf16x8 vf = *(const bf16x8*)&Vs[ksb * 4096 + (dt * 16 + l15) * 32 + quad * 8];
        accO[dt] = __builtin_amdgcn_mfma_f32_16x16x32_bf16(pf[ksb], vf, accO[dt], 0, 0, 0);
      }
    }
  }
  // ---- epilogue: normalize by l (broadcast like alpha) and store ----
  const float linv = 1.f / lrow;
  float li[4];
#pragma unroll
  for (int r = 0; r < 4; r++) li[r] = __shfl(linv, quad * 4 + r, 64);
#pragma unroll
  for (int r = 0; r < 4; r++) {
    const long srow = (long)qb * 64 + wave * 16 + quad * 4 + r;
#pragma unroll
    for (int dt = 0; dt < 8; dt++)
      o_bf[srow * HIDN + h * HDIM + dt * 16 + l15] = f2bf(accO[dt][r] * li[r]);
  }
}

// ---------------- workspace layout ----------------
static constexpr size_t SZ_WQKVT = (size_t)NQKV * HIDN * 2;
static constexpr size_t SZ_WOT = (size_t)HIDN * HIDN * 2;
static constexpr size_t SZ_WBIG = (size_t)INTER * HIDN * 2;
static constexpr size_t OFF_WQKVT = 0;
static constexpr size_t OFF_WOT = OFF_WQKVT + SZ_WQKVT;
static constexpr size_t OFF_WGATET = OFF_WOT + SZ_WOT;
static constexpr size_t OFF_WUPT = OFF_WGATET + SZ_WBIG;
static constexpr size_t OFF_WDOWNT = OFF_WUPT + SZ_WBIG;
static constexpr size_t OFF_BIAS = OFF_WDOWNT + SZ_WBIG;
static constexpr size_t OFF_MASK = OFF_BIAS + 3072 * 4 + 4096;
static constexpr size_t OFF_QM = OFF_MASK + 16 * 32 * 32 + 4096;
static constexpr size_t OFF_KM = OFF_QM + (size_t)32 * 16 * 128 * 4;
static constexpr size_t OFF_QG = OFF_KM + (size_t)32 * 4 * 128 * 4;
static constexpr size_t OFF_KG = OFF_QG + (size_t)32 * 16 * 128 * 4;
static constexpr size_t OFF_H2 = OFF_KG + (size_t)32 * 4 * 128 * 4;
static constexpr size_t OFF_H3 = OFF_H2 + (size_t)S_LEN * HIDN * 4;
static constexpr size_t OFF_REGA = OFF_H3 + (size_t)S_LEN * HIDN * 2;
//   REGA phase1: h_bf | q_bf | k_bf | v_t | o_bf ; phase2: act_bf (o_bf dead)
static constexpr size_t RA_HBF = 0;
static constexpr size_t RA_QBF = RA_HBF + (size_t)S_LEN * HIDN * 2;
static constexpr size_t RA_KBF = RA_QBF + (size_t)HQ * S_LEN * HDIM * 2;
static constexpr size_t RA_VT = RA_KBF + (size_t)HKV * S_LEN * HDIM * 2;
static constexpr size_t RA_OBF = RA_VT + (size_t)HKV * HDIM * S_LEN * 2;
static constexpr size_t SZ_REGA = RA_OBF + (size_t)S_LEN * HIDN * 2;
static constexpr size_t OFF_REGB = OFF_REGA + SZ_REGA;
//   REGB phase1: qkv_f32 (S x 3072 f32) ; phase2: g_bf (S x INTER bf16)
static constexpr size_t SZ_REGB = (size_t)S_LEN * NQKV * 4;
static constexpr size_t TOTAL_WS = OFF_REGB + SZ_REGB;

extern "C" void kernel_launch(void* const* d_in, const int* in_sizes, int n_in,
                              void* d_out, int out_size, void* d_ws, size_t ws_size,
                              hipStream_t stream) {
  const float* hidden = (const float*)d_in[0];
  const float* cosb = (const float*)d_in[1];
  const float* sinb = (const float*)d_in[2];
  const float* ln1 = (const float*)d_in[3];
  const float* ln2 = (const float*)d_in[4];
  const float* Wq = (const float*)d_in[5];
  const float* bq = (const float*)d_in[6];
  const float* Wk = (const float*)d_in[7];
  const float* bk = (const float*)d_in[8];
  const float* Wv = (const float*)d_in[9];
  const float* bv = (const float*)d_in[10];
  const float* Wo = (const float*)d_in[11];
  const float* gWq = (const float*)d_in[12];
  const float* gWk = (const float*)d_in[13];
  const float* Wgate = (const float*)d_in[14];
  const float* Wup = (const float*)d_in[15];
  const float* Wdown = (const float*)d_in[16];

  if (ws_size < TOTAL_WS) return;  // workspace too small; fail visibly

  char* ws = (char*)d_ws;
  short* WqkvT = (short*)(ws + OFF_WQKVT);
  short* WoT = (short*)(ws + OFF_WOT);
  short* WgateT = (short*)(ws + OFF_WGATET);
  short* WupT = (short*)(ws + OFF_WUPT);
  short* WdownT = (short*)(ws + OFF_WDOWNT);
  float* biasqkv = (float*)(ws + OFF_BIAS);
  unsigned char* maskb = (unsigned char*)(ws + OFF_MASK);
  float* qm = (float*)(ws + OFF_QM);
  float* km = (float*)(ws + OFF_KM);
  float* qg = (float*)(ws + OFF_QG);
  float* kg = (float*)(ws + OFF_KG);
  float* h2 = (float*)(ws + OFF_H2);
  short* h3_bf = (short*)(ws + OFF_H3);
  short* h_bf = (short*)(ws + OFF_REGA + RA_HBF);
  short* q_bf = (short*)(ws + OFF_REGA + RA_QBF);
  short* k_bf = (short*)(ws + OFF_REGA + RA_KBF);
  short* v_t = (short*)(ws + OFF_REGA + RA_VT);
  short* o_bf = (short*)(ws + OFF_REGA + RA_OBF);
  short* act_bf = (short*)(ws + OFF_REGA);  // overlays h_bf..v_t, all dead by then
  float* qkv_f = (float*)(ws + OFF_REGB);
  short* g_bf = (short*)(ws + OFF_REGB);  // overlays qkv_f, dead by then
  float* outp = (float*)d_out;

  dim3 tb(32, 8);
  // weight transposes (fp32 -> bf16, N x K)
  k_transpose_cast<<<dim3(64, 64), tb, 0, stream>>>(Wq, WqkvT, HIDN, 2048);
  k_transpose_cast<<<dim3(16, 64), tb, 0, stream>>>(Wk, WqkvT + (size_t)2048 * HIDN, HIDN, 512);
  k_transpose_cast<<<dim3(16, 64), tb, 0, stream>>>(Wv, WqkvT + (size_t)2560 * HIDN, HIDN, 512);
  k_transpose_cast<<<dim3(64, 64), tb, 0, stream>>>(Wo, WoT, HIDN, HIDN);
  k_transpose_cast<<<dim3(176, 64), tb, 0, stream>>>(Wgate, WgateT, HIDN, INTER);
  k_transpose_cast<<<dim3(176, 64), tb, 0, stream>>>(Wup, WupT, HIDN, INTER);
  k_transpose_cast<<<dim3(64, 176), tb, 0, stream>>>(Wdown, WdownT, INTER, HIDN);
  k_bias_concat<<<12, 256, 0, stream>>>(bq, bk, bv, biasqkv);

  // h = RMS(hidden, ln1) -> bf16
  k_rms<<<S_LEN, 256, 0, stream>>>(hidden, ln1, h_bf);
  // qkv = h @ [Wq|Wk|Wv] + bias  (fp32)
  k_gemm<0, 128><<<dim3(NQKV / 128, S_LEN / 128), 256, 0, stream>>>(
      h_bf, WqkvT, qkv_f, nullptr, biasqkv, nullptr, nullptr, S_LEN, NQKV, HIDN);
  // gate path (pre-RoPE q,k)
  k_blockmean<<<320, 256, 0, stream>>>(qkv_f, qm, km);
  k_gateproj<<<640, 128, 0, stream>>>(qm, km, gWq, gWk, qg, kg);
  k_gatemask<<<dim3(32, 16), 64, 0, stream>>>(qg, kg, maskb);
  // RoPE + layout change
  k_rope<<<10240, 256, 0, stream>>>(qkv_f, cosb, sinb, q_bf, k_bf);
  k_vcast_t<<<dim3(4, 64, 4), tb, 0, stream>>>(qkv_f, v_t);
  // attention
  k_attn<<<dim3(32, 16), 256, 0, stream>>>(q_bf, k_bf, v_t, maskb, o_bf);
  // h2 = o @ Wo + hidden (fp32)
  k_gemm<0, 128><<<dim3(HIDN / 128, S_LEN / 128), 256, 0, stream>>>(
      o_bf, WoT, h2, nullptr, nullptr, hidden, nullptr, S_LEN, HIDN, HIDN);
  // h3 = RMS(h2, ln2) -> bf16
  k_rms<<<S_LEN, 256, 0, stream>>>(h2, ln2, h3_bf);
  // g = h3 @ Wgate (bf16)
  k_gemm<1, 128><<<dim3(INTER / 128, 16), 256, 0, stream>>>(
      h3_bf, WgateT, nullptr, g_bf, nullptr, nullptr, nullptr, S_LEN, INTER, HIDN);
  // act = silu(g) * (h3 @ Wup) (bf16)
  k_gemm<2, 128><<<dim3(INTER / 128, 16), 256, 0, stream>>>(
      h3_bf, WupT, nullptr, act_bf, nullptr, nullptr, g_bf, S_LEN, INTER, HIDN);
  // out = act @ Wdown + h2 (fp32)
  k_gemm<0, 128><<<dim3(HIDN / 128, S_LEN / 128), 256, 0, stream>>>(
      act_bf, WdownT, outp, nullptr, nullptr, h2, nullptr, S_LEN, HIDN, INTER);
  (void)in_sizes; (void)n_in; (void)out_size;
}

// Round 2
// 699.751 us; speedup vs baseline: 1.0471x; 1.0471x over previous
//
#include <hip/hip_runtime.h>
#include <stdint.h>
#include <stddef.h>

// ---------------- problem constants ----------------
#define S_LEN 2048
#define HIDN  2048
#define HQ    16
#define HKV   4
#define HDIM  128
#define NQKV  3072      // HQ*D + 2*HKV*D
#define QBLK  32        // S/64
#define GHW   128
#define INTER 5632
#define NEGF  (-1e30f)
#define THRG  0.004f

typedef short bf16x8 __attribute__((ext_vector_type(8)));
typedef float f32x4  __attribute__((ext_vector_type(4)));

__device__ __forceinline__ short f2bf(float f) {
  union { float f; unsigned u; } v; v.f = f;
  unsigned r = (v.u + 0x7FFFu + ((v.u >> 16) & 1u)) >> 16;
  return (short)r;
}
__device__ __forceinline__ float bf2f(short s) {
  union { float f; unsigned u; } v; v.u = ((unsigned)(unsigned short)s) << 16;
  return v.f;
}
__device__ __forceinline__ void gload16(const void* g, void* l) {
  __builtin_amdgcn_global_load_lds(
      (const __attribute__((address_space(1))) void*)g,
      (__attribute__((address_space(3))) void*)l, 16, 0, 0);
}
// pack two f32 -> [bf16(hi)<<16 | bf16(lo)] via byte-select (truncation)
__device__ __forceinline__ unsigned pack_bf2(float hi, float lo) {
  return __builtin_amdgcn_perm(__float_as_uint(hi), __float_as_uint(lo), 0x07060302u);
}

// ---------------- transpose + cast fp32 (R x C) -> bf16 (C x R) ----------------
__global__ __launch_bounds__(256) void k_transpose_cast(
    const float* __restrict__ src, short* __restrict__ dst, int R, int C) {
  __shared__ float t[32][33];
  const int tx = threadIdx.x, ty = threadIdx.y;
  const int x = blockIdx.x * 32 + tx;
  const int y0 = blockIdx.y * 32;
#pragma unroll
  for (int i = 0; i < 4; i++) {
    int yy = ty + i * 8;
    t[yy][tx] = src[(long)(y0 + yy) * C + x];
  }
  __syncthreads();
  const int xo = blockIdx.y * 32 + tx;
  const int yo0 = blockIdx.x * 32;
#pragma unroll
  for (int i = 0; i < 4; i++) {
    int yy = ty + i * 8;
    dst[(long)(yo0 + yy) * R + xo] = f2bf(t[tx][yy]);
  }
}

// ---------------- concat qkv bias ----------------
__global__ void k_bias_concat(const float* __restrict__ bq, const float* __restrict__ bk,
                              const float* __restrict__ bv, float* __restrict__ out) {
  int i = blockIdx.x * 256 + threadIdx.x;
  if (i < 2048) out[i] = bq[i];
  else if (i < 2560) out[i] = bk[i - 2048];
  else out[i] = bv[i - 2560];
}

// ---------------- RMSNorm fp32 -> bf16 ----------------
__global__ __launch_bounds__(256) void k_rms(const float* __restrict__ x,
                                             const float* __restrict__ w,
                                             short* __restrict__ out) {
  const int row = blockIdx.x;
  const float* xr = x + (long)row * HIDN;
  float v[8];
  float ss = 0.f;
#pragma unroll
  for (int i = 0; i < 8; i++) {
    v[i] = xr[threadIdx.x + i * 256];
    ss += v[i] * v[i];
  }
#pragma unroll
  for (int off = 32; off > 0; off >>= 1) ss += __shfl_down(ss, off, 64);
  __shared__ float red[4];
  const int wave = threadIdx.x >> 6, lane = threadIdx.x & 63;
  if (lane == 0) red[wave] = ss;
  __syncthreads();
  float tot = red[0] + red[1] + red[2] + red[3];
  float rs = rsqrtf(tot / (float)HIDN + 1e-6f);
#pragma unroll
  for (int i = 0; i < 8; i++) {
    int c = threadIdx.x + i * 256;
    out[(long)row * HIDN + c] = f2bf(v[i] * rs * w[c]);
  }
}

// ---------------- GEMM: C[M,N] = A[M,K](bf16) * Bt[N,K](bf16)^T  ----------------
// MODE 0: Cf = acc + bias? + add?   (fp32 out)
// MODE 4: split-K partial: z==0 -> Cf, z==1 -> Cf2 (no bias/add)
// BK=64: tiles stored as two k-half panels [2][rows][32].
// ksl = K-slice length per z (== K when gridDim.z == 1).
template <int MODE, int BN>
__global__ __launch_bounds__(256) void k_gemm(
    const short* __restrict__ A, const short* __restrict__ Bt,
    float* __restrict__ Cf, float* __restrict__ Cf2,
    const float* __restrict__ bias, const float* __restrict__ add,
    int M, int N, int K, int ksl) {
  constexpr int NT = BN / 32;   // n-tiles per wave
  constexpr int BIW = BN / 32;  // per-wave B staging instrs
  constexpr int BPP = BN / 16;  // B staging instrs per k-half panel
  __shared__ short As[2][128][32];
  __shared__ short Bs[2][BN][32];
  const int tid = threadIdx.x;
  const int wave = tid >> 6, lane = tid & 63, quad = lane >> 4, l15 = lane & 15;
  const long m0 = (long)blockIdx.y * 128, n0 = (long)blockIdx.x * BN;
  const int wr = (wave >> 1) * 64, wc = (wave & 1) * (BN / 2);
  const int i2 = lane >> 2, i3 = lane & 3;
  f32x4 acc[4][NT] = {};
  // A staging: 16 instrs (4/wave). instr g: k-half h=g>>3, rows (g&7)*16..+15
  const short* Ainst[4];
  short* Alds[4];
#pragma unroll
  for (int j = 0; j < 4; j++) {
    const int g = wave * 4 + j, h = g >> 3, rb = (g & 7) * 16;
    Ainst[j] = A + (m0 + rb + i2) * K + h * 32 + i3 * 8;
    Alds[j] = &As[h][rb][0];
  }
  // B staging: BN/8 instrs (BIW/wave)
  const short* Binst[BIW];
  short* Blds[BIW];
#pragma unroll
  for (int j = 0; j < BIW; j++) {
    const int g = wave * BIW + j, h = g / BPP, rb = (g % BPP) * 16;
    Binst[j] = Bt + (n0 + rb + i2) * K + h * 32 + i3 * 8;
    Blds[j] = &Bs[h][rb][0];
  }
  const int kbeg = blockIdx.z * ksl;
  const int kend = kbeg + ksl;
  for (int k0 = kbeg; k0 < kend; k0 += 64) {
    __syncthreads();
#pragma unroll
    for (int j = 0; j < 4; j++) gload16(Ainst[j] + k0, Alds[j]);
#pragma unroll
    for (int j = 0; j < BIW; j++) gload16(Binst[j] + k0, Blds[j]);
    __syncthreads();
#pragma unroll
    for (int s = 0; s < 2; s++) {
      bf16x8 af[4], bb[NT];
#pragma unroll
      for (int mi = 0; mi < 4; mi++)
        af[mi] = *(const bf16x8*)&As[s][wr + mi * 16 + l15][quad * 8];
#pragma unroll
      for (int ni = 0; ni < NT; ni++)
        bb[ni] = *(const bf16x8*)&Bs[s][wc + ni * 16 + l15][quad * 8];
#pragma unroll
      for (int mi = 0; mi < 4; mi++)
#pragma unroll
        for (int ni = 0; ni < NT; ni++)
          acc[mi][ni] = __builtin_amdgcn_mfma_f32_16x16x32_bf16(af[mi], bb[ni], acc[mi][ni], 0, 0, 0);
    }
  }
  const bool hb = (MODE == 0) && (bias != nullptr);
  const bool ha = (MODE == 0) && (add != nullptr);
  float* dstp = (MODE == 4) ? ((blockIdx.z == 0) ? Cf : Cf2) : Cf;
#pragma unroll
  for (int mi = 0; mi < 4; mi++) {
#pragma unroll
    for (int ni = 0; ni < NT; ni++) {
      long mbase = m0 + wr + mi * 16 + quad * 4;
      long n = n0 + wc + ni * 16 + l15;
#pragma unroll
      for (int r = 0; r < 4; r++) {
        float v = acc[mi][ni][r];
        long idx = (mbase + r) * N + n;
        if (MODE == 0) {
          if (hb) v += bias[n];
          if (ha) v += add[idx];
          Cf[idx] = v;
        } else {
          dstp[idx] = v;
        }
      }
    }
  }
}

// ---------------- fused gate/up GEMM: Cb = bf16(silu(A@Bg^T) * (A@Bu^T)) ----------------
// BN=128, shared A staging, two B panels, two accumulator sets.
// 64 MFMA per wave per K-step vs 32 in the single kernel (same 2 barriers).
__global__ __launch_bounds__(256) void k_gemm_gu(
    const short* __restrict__ A, const short* __restrict__ Bg,
    const short* __restrict__ Bu, short* __restrict__ Cb,
    int M, int N, int K) {
  __shared__ short As[2][128][32];
  __shared__ short Gs[2][128][32];
  __shared__ short Us[2][128][32];
  const int tid = threadIdx.x;
  const int wave = tid >> 6, lane = tid & 63, quad = lane >> 4, l15 = lane & 15;
  const long m0 = (long)blockIdx.y * 128, n0 = (long)blockIdx.x * 128;
  const int wr = (wave >> 1) * 64, wc = (wave & 1) * 64;
  const int i2 = lane >> 2, i3 = lane & 3;
  const long uoff = (long)(Bu - Bg);
  f32x4 accg[4][4] = {}, accu[4][4] = {};
  const short* Ainst[4];
  short* Alds[4];
  const short* Ginst[4];
  short* Glds[4];
  short* Ulds[4];
#pragma unroll
  for (int j = 0; j < 4; j++) {
    const int g = wave * 4 + j, h = g >> 3, rb = (g & 7) * 16;
    Ainst[j] = A + (m0 + rb + i2) * K + h * 32 + i3 * 8;
    Alds[j] = &As[h][rb][0];
    Ginst[j] = Bg + (n0 + rb + i2) * K + h * 32 + i3 * 8;
    Glds[j] = &Gs[h][rb][0];
    Ulds[j] = &Us[h][rb][0];
  }
  for (int k0 = 0; k0 < K; k0 += 64) {
    __syncthreads();
#pragma unroll
    for (int j = 0; j < 4; j++) {
      gload16(Ainst[j] + k0, Alds[j]);
      gload16(Ginst[j] + k0, Glds[j]);
      gload16(Ginst[j] + k0 + uoff, Ulds[j]);
    }
    __syncthreads();
#pragma unroll
    for (int s = 0; s < 2; s++) {
      bf16x8 af[4], bg[4], bu[4];
#pragma unroll
      for (int mi = 0; mi < 4; mi++)
        af[mi] = *(const bf16x8*)&As[s][wr + mi * 16 + l15][quad * 8];
#pragma unroll
      for (int ni = 0; ni < 4; ni++) {
        bg[ni] = *(const bf16x8*)&Gs[s][wc + ni * 16 + l15][quad * 8];
        bu[ni] = *(const bf16x8*)&Us[s][wc + ni * 16 + l15][quad * 8];
      }
#pragma unroll
      for (int mi = 0; mi < 4; mi++)
#pragma unroll
        for (int ni = 0; ni < 4; ni++) {
          accg[mi][ni] = __builtin_amdgcn_mfma_f32_16x16x32_bf16(af[mi], bg[ni], accg[mi][ni], 0, 0, 0);
          accu[mi][ni] = __builtin_amdgcn_mfma_f32_16x16x32_bf16(af[mi], bu[ni], accu[mi][ni], 0, 0, 0);
        }
    }
  }
#pragma unroll
  for (int mi = 0; mi < 4; mi++) {
#pragma unroll
    for (int ni = 0; ni < 4; ni++) {
      long mbase = m0 + wr + mi * 16 + quad * 4;
      long n = n0 + wc + ni * 16 + l15;
#pragma unroll
      for (int r = 0; r < 4; r++) {
        float g = accg[mi][ni][r];
        float u = accu[mi][ni][r];
        float sg = g / (1.f + __expf(-g));
        Cb[(mbase + r) * N + n] = f2bf(sg * u);
      }
    }
  }
}

// ---------------- final reduce: out = out(partial1) + p0 + h2 ----------------
__global__ __launch_bounds__(256) void k_finish(const float* __restrict__ p0,
                                                const float* __restrict__ h2,
                                                float* __restrict__ out) {
  const long n = (long)S_LEN * HIDN;
  for (long i = ((long)blockIdx.x * 256 + threadIdx.x) * 4; i < n;
       i += (long)gridDim.x * 256 * 4) {
    float4 a = *(const float4*)(out + i);
    float4 b = *(const float4*)(p0 + i);
    float4 c = *(const float4*)(h2 + i);
    a.x += b.x + c.x;
    a.y += b.y + c.y;
    a.z += b.z + c.z;
    a.w += b.w + c.w;
    *(float4*)(out + i) = a;
  }
}

// ---------------- block means of q and k (pre-RoPE) ----------------
__global__ __launch_bounds__(256) void k_blockmean(const float* __restrict__ qkv,
                                                   float* __restrict__ qm,
                                                   float* __restrict__ km) {
  int id = blockIdx.x * 256 + threadIdx.x;  // 32 * 2560
  int qb = id / 2560, c = id % 2560;        // cols 0..2559 = q(2048) + k(512)
  const float* base = qkv + (long)qb * 64 * NQKV + c;
  float acc = 0.f;
  for (int s = 0; s < 64; s++) acc += base[(long)s * NQKV];
  acc *= (1.f / 64.f);
  if (c < 2048) qm[(long)qb * 2048 + c] = acc;
  else km[(long)qb * 512 + (c - 2048)] = acc;
}

// ---------------- gate projections qg = qm@gWq, kg = km@gWk ----------------
__global__ __launch_bounds__(128) void k_gateproj(const float* __restrict__ qm,
                                                  const float* __restrict__ km,
                                                  const float* __restrict__ gWq,
                                                  const float* __restrict__ gWk,
                                                  float* __restrict__ qg,
                                                  float* __restrict__ kg) {
  __shared__ float xm[128];
  const int b = blockIdx.x;
  const float* src; const float* W; float* dst;
  if (b < 512) { src = qm + (long)b * 128; W = gWq; dst = qg + (long)b * 128; }
  else { int r = b - 512; src = km + (long)r * 128; W = gWk; dst = kg + (long)r * 128; }
  xm[threadIdx.x] = src[threadIdx.x];
  __syncthreads();
  float acc = 0.f;
  for (int d = 0; d < 128; d++) acc += xm[d] * W[d * GHW + threadIdx.x];
  dst[threadIdx.x] = acc;
}

// ---------------- gate softmax + keep mask ----------------
__global__ __launch_bounds__(64) void k_gatemask(const float* __restrict__ qg,
                                                 const float* __restrict__ kg,
                                                 unsigned char* __restrict__ mask) {
  const int qb = blockIdx.x, h = blockIdx.y;
  __shared__ float qv[128];
  const int t = threadIdx.x;
  qv[t] = qg[((long)qb * 16 + h) * 128 + t];
  qv[t + 64] = qg[((long)qb * 16 + h) * 128 + t + 64];
  __syncthreads();
  const int kb = t;
  float s = NEGF;
  if (kb < 32 && kb <= qb) {
    const float* kr = kg + ((long)kb * 4 + (h >> 2)) * 128;
    float acc = 0.f;
    for (int d = 0; d < 128; d++) acc += qv[d] * kr[d];
    s = acc * 0.08838834764831845f;  // GH^-0.5
  }
  float m = s;
#pragma unroll
  for (int off = 32; off > 0; off >>= 1) m = fmaxf(m, __shfl_xor(m, off, 64));
  float e = (kb < 32 && kb <= qb) ? __expf(s - m) : 0.f;
  float sum = e;
#pragma unroll
  for (int off = 32; off > 0; off >>= 1) sum += __shfl_xor(sum, off, 64);
  if (kb < 32) {
    float gate = e / sum;
    bool keep = (kb <= qb) && (gate >= THRG || kb == qb);
    mask[((long)h * 32 + qb) * 32 + kb] = keep ? 1 : 0;
  }
}

// ---------------- RoPE + cast q,k -> head-major bf16 ----------------
__global__ __launch_bounds__(256) void k_rope(const float* __restrict__ qkv,
                                              const float* __restrict__ cosb,
                                              const float* __restrict__ sinb,
                                              short* __restrict__ q_bf,
                                              short* __restrict__ k_bf) {
  long id = (long)blockIdx.x * 256 + threadIdx.x;  // S * 20 * 64
  int d = (int)(id & 63);
  long rest = id >> 6;
  int head = (int)(rest % 20);
  int s = (int)(rest / 20);
  const float c = cosb[(long)s * HDIM + d];
  const float sn = sinb[(long)s * HDIM + d];
  if (head < HQ) {
    const float* src = qkv + (long)s * NQKV + head * HDIM;
    float x1 = src[d], x2 = src[d + 64];
    short* dst = q_bf + ((long)head * S_LEN + s) * HDIM;
    dst[d] = f2bf(x1 * c - x2 * sn);
    dst[d + 64] = f2bf(x2 * c + x1 * sn);
  } else {
    int hk = head - HQ;
    const float* src = qkv + (long)s * NQKV + 2048 + hk * HDIM;
    float x1 = src[d], x2 = src[d + 64];
    short* dst = k_bf + ((long)hk * S_LEN + s) * HDIM;
    dst[d] = f2bf(x1 * c - x2 * sn);
    dst[d + 64] = f2bf(x2 * c + x1 * sn);
  }
}

// ---------------- v transpose-cast (tiled, coalesced): v_t[hk][d][s] ----------------
__global__ __launch_bounds__(256) void k_vcast_t(const float* __restrict__ qkv,
                                                 short* __restrict__ v_t) {
  __shared__ float t[32][33];
  const int hk = blockIdx.z;
  const int tx = threadIdx.x, ty = threadIdx.y;  // 32 x 8
  const int d0 = blockIdx.x * 32;                // within HDIM
  const int s0 = blockIdx.y * 32;                // within S
  const float* src = qkv + 2560 + (long)hk * HDIM;
#pragma unroll
  for (int i = 0; i < 4; i++) {
    int s = ty + i * 8;
    t[s][tx] = src[(long)(s0 + s) * NQKV + d0 + tx];
  }
  __syncthreads();
  short* dst = v_t + (long)hk * HDIM * S_LEN;
#pragma unroll
  for (int i = 0; i < 4; i++) {
    int d = ty + i * 8;
    dst[(long)(d0 + d) * S_LEN + s0 + tx] = f2bf(t[tx][d]);
  }
}

// ---------------- flash attention: LDS staging + S^T register softmax ----------------
__global__ __launch_bounds__(256) void k_attn(const short* __restrict__ q_bf,
                                              const short* __restrict__ k_bf,
                                              const short* __restrict__ v_t,
                                              const unsigned char* __restrict__ mask,
                                              short* __restrict__ o_bf) {
  const int qb = blockIdx.x, h = blockIdx.y;
  const int tid = threadIdx.x, wave = tid >> 6, lane = tid & 63;
  const int quad = lane >> 4, l15 = lane & 15;
  __shared__ short Ks[4 * 64 * 32];   // panel kd: [row r][32]
  __shared__ short Vs[2 * 128 * 32];  // panel ksb: [d][32]
  __shared__ short Ps[4][16 * 72];    // per-wave P, padded stride 72 shorts
  short* Pw = Ps[wave];
  const int hk = h >> 2;
  const unsigned char* mptr = mask + ((long)h * 32 + qb) * 32;
  const float SCL = 0.08838834764831845f * 1.4426950408889634f;  // D^-.5 * log2e
  const int qrow_g = qb * 64 + wave * 16 + l15;  // this lane's q-row

  // Q B-frags (n = q-row indexed by l15), resident all kernel
  bf16x8 bq[4];
  {
    const short* qrp = q_bf + ((long)h * S_LEN + qrow_g) * HDIM + quad * 8;
#pragma unroll
    for (int kd = 0; kd < 4; kd++) bq[kd] = *(const bf16x8*)(qrp + kd * 32);
  }

  const short* kh = k_bf + (long)hk * S_LEN * HDIM;
  const short* vh = v_t + (long)hk * HDIM * S_LEN;

  const int i2 = lane >> 2, i3 = lane & 3;
  int koff[4], voff[4];
  const int vp = wave >> 1, vhh = wave & 1;
#pragma unroll
  for (int inst = 0; inst < 4; inst++) {
    koff[inst] = (inst * 16 + i2) * HDIM + wave * 32 + i3 * 8;
    voff[inst] = (vhh * 64 + inst * 16 + i2) * S_LEN + vp * 32 + i3 * 8;
  }

  f32x4 accO[8] = {};
  float mrow = -3.0e38f, lrow = 0.f;

  for (int kb = 0; kb <= qb; kb++) {
    if (!mptr[kb]) continue;  // block-uniform
    __syncthreads();  // prior iter's LDS reads done before overwrite
    {
      const int kg = kb * 64 * HDIM;
      const int vg = kb * 64;
#pragma unroll
      for (int inst = 0; inst < 4; inst++) {
        gload16(kh + kg + koff[inst], &Ks[wave * 2048 + inst * 512]);
        gload16(vh + vg + voff[inst], &Vs[vp * 4096 + (vhh * 64 + inst * 16) * 32]);
      }
    }
    __syncthreads();  // all staging landed (compiler drains vmcnt)

    // ---- S^T: 4 subtiles; lane ends with 16 scores for its q-row ----
    f32x4 sv[4];
#pragma unroll
    for (int nt = 0; nt < 4; nt++) {
      f32x4 t = {};
#pragma unroll
      for (int kd = 0; kd < 4; kd++) {
        bf16x8 ka = *(const bf16x8*)&Ks[kd * 2048 + (nt * 16 + l15) * 32 + quad * 8];
        t = __builtin_amdgcn_mfma_f32_16x16x32_bf16(ka, bq[kd], t, 0, 0, 0);
      }
      sv[nt] = t;
    }
    // ---- scale + mask + row max ----
    float lmx = -__builtin_inff();
    if (kb < qb) {
#pragma unroll
      for (int nt = 0; nt < 4; nt++)
#pragma unroll
        for (int r = 0; r < 4; r++) {
          sv[nt][r] *= SCL;
          lmx = fmaxf(lmx, sv[nt][r]);
        }
    } else {  // diagonal block
#pragma unroll
      for (int nt = 0; nt < 4; nt++)
#pragma unroll
        for (int r = 0; r < 4; r++) {
          const int kcol = kb * 64 + nt * 16 + quad * 4 + r;
          sv[nt][r] = (kcol <= qrow_g) ? sv[nt][r] * SCL : -__builtin_inff();
          lmx = fmaxf(lmx, sv[nt][r]);
        }
    }
    lmx = fmaxf(lmx, __shfl_xor(lmx, 16, 64));
    lmx = fmaxf(lmx, __shfl_xor(lmx, 32, 64));
    const float mnew = fmaxf(mrow, lmx);
    const float alpha = __builtin_amdgcn_exp2f(mrow - mnew);
    mrow = mnew;
    // ---- exp2 + sum + packed P write (padded stride, b64) ----
    float psum = 0.f;
#pragma unroll
    for (int nt = 0; nt < 4; nt++) {
#pragma unroll
      for (int r = 0; r < 4; r++) {
        float p = __builtin_amdgcn_exp2f(sv[nt][r] - mnew);
        sv[nt][r] = p;
        psum += p;
      }
      uint2 u;
      u.x = pack_bf2(sv[nt][1], sv[nt][0]);
      u.y = pack_bf2(sv[nt][3], sv[nt][2]);
      *(uint2*)&Pw[l15 * 72 + nt * 16 + quad * 4] = u;
    }
    psum += __shfl_xor(psum, 16, 64);
    psum += __shfl_xor(psum, 32, 64);
    lrow = lrow * alpha + psum;
    // ---- rescale accO (alpha broadcast: lane j<16 holds row j's alpha) ----
    float al[4];
#pragma unroll
    for (int r = 0; r < 4; r++) al[r] = __shfl(alpha, quad * 4 + r, 64);
#pragma unroll
    for (int dt = 0; dt < 8; dt++)
#pragma unroll
      for (int r = 0; r < 4; r++) accO[dt][r] *= al[r];
    // drain this wave's P writes before fragment reads (per-wave buffer)
    asm volatile("s_waitcnt lgkmcnt(0)" ::: "memory");
    // ---- PV: P(16x64) @ V^T panels ----
    bf16x8 pf[2];
#pragma unroll
    for (int ksb = 0; ksb < 2; ksb++)
      pf[ksb] = *(const bf16x8*)&Pw[l15 * 72 + ksb * 32 + quad * 8];
#pragma unroll
    for (int dt = 0; dt < 8; dt++) {
#pragma unroll
      for (int ksb = 0; ksb < 2; ksb++) {
        bf16x8 vf = *(const bf16x8*)&Vs[ksb * 4096 + (dt * 16 + l15) * 32 + quad * 8];
        accO[dt] = __builtin_amdgcn_mfma_f32_16x16x32_bf16(pf[ksb], vf, accO[dt], 0, 0, 0);
      }
    }
  }
  // ---- epilogue: normalize by l (broadcast like alpha) and store ----
  const float linv = 1.f / lrow;
  float li[4];
#pragma unroll
  for (int r = 0; r < 4; r++) li[r] = __shfl(linv, quad * 4 + r, 64);
#pragma unroll
  for (int r = 0; r < 4; r++) {
    const long srow = (long)qb * 64 + wave * 16 + quad * 4 + r;
#pragma unroll
    for (int dt = 0; dt < 8; dt++)
      o_bf[srow * HIDN + h * HDIM + dt * 16 + l15] = f2bf(accO[dt][r] * li[r]);
  }
}

// ---------------- workspace layout ----------------
static constexpr size_t SZ_WQKVT = (size_t)NQKV * HIDN * 2;
static constexpr size_t SZ_WOT = (size_t)HIDN * HIDN * 2;
static constexpr size_t SZ_WBIG = (size_t)INTER * HIDN * 2;
static constexpr size_t OFF_WQKVT = 0;
static constexpr size_t OFF_WOT = OFF_WQKVT + SZ_WQKVT;
static constexpr size_t OFF_WGATET = OFF_WOT + SZ_WOT;
static constexpr size_t OFF_WUPT = OFF_WGATET + SZ_WBIG;   // MUST stay adjacent to WGATET (k_gemm_gu uoff)
static constexpr size_t OFF_WDOWNT = OFF_WUPT + SZ_WBIG;
static constexpr size_t OFF_BIAS = OFF_WDOWNT + SZ_WBIG;
static constexpr size_t OFF_MASK = OFF_BIAS + 3072 * 4 + 4096;
static constexpr size_t OFF_QM = OFF_MASK + 16 * 32 * 32 + 4096;
static constexpr size_t OFF_KM = OFF_QM + (size_t)32 * 16 * 128 * 4;
static constexpr size_t OFF_QG = OFF_KM + (size_t)32 * 4 * 128 * 4;
static constexpr size_t OFF_KG = OFF_QG + (size_t)32 * 16 * 128 * 4;
static constexpr size_t OFF_H2 = OFF_KG + (size_t)32 * 4 * 128 * 4;
static constexpr size_t OFF_H3 = OFF_H2 + (size_t)S_LEN * HIDN * 4;
static constexpr size_t OFF_REGA = OFF_H3 + (size_t)S_LEN * HIDN * 2;
//   REGA phase1: h_bf | q_bf | k_bf | v_t | o_bf ; phase2: act_bf (o_bf dead)
static constexpr size_t RA_HBF = 0;
static constexpr size_t RA_QBF = RA_HBF + (size_t)S_LEN * HIDN * 2;
static constexpr size_t RA_KBF = RA_QBF + (size_t)HQ * S_LEN * HDIM * 2;
static constexpr size_t RA_VT = RA_KBF + (size_t)HKV * S_LEN * HDIM * 2;
static constexpr size_t RA_OBF = RA_VT + (size_t)HKV * HDIM * S_LEN * 2;
static constexpr size_t SZ_REGA = RA_OBF + (size_t)S_LEN * HIDN * 2;
static constexpr size_t OFF_REGB = OFF_REGA + SZ_REGA;
//   REGB phase1: qkv_f32 (S x 3072 f32) ; phase2: p0 split-K partial (S x HIDN f32)
static constexpr size_t SZ_REGB = (size_t)S_LEN * NQKV * 4;
static constexpr size_t TOTAL_WS = OFF_REGB + SZ_REGB;

extern "C" void kernel_launch(void* const* d_in, const int* in_sizes, int n_in,
                              void* d_out, int out_size, void* d_ws, size_t ws_size,
                              hipStream_t stream) {
  const float* hidden = (const float*)d_in[0];
  const float* cosb = (const float*)d_in[1];
  const float* sinb = (const float*)d_in[2];
  const float* ln1 = (const float*)d_in[3];
  const float* ln2 = (const float*)d_in[4];
  const float* Wq = (const float*)d_in[5];
  const float* bq = (const float*)d_in[6];
  const float* Wk = (const float*)d_in[7];
  const float* bk = (const float*)d_in[8];
  const float* Wv = (const float*)d_in[9];
  const float* bv = (const float*)d_in[10];
  const float* Wo = (const float*)d_in[11];
  const float* gWq = (const float*)d_in[12];
  const float* gWk = (const float*)d_in[13];
  const float* Wgate = (const float*)d_in[14];
  const float* Wup = (const float*)d_in[15];
  const float* Wdown = (const float*)d_in[16];

  if (ws_size < TOTAL_WS) return;  // workspace too small; fail visibly

  char* ws = (char*)d_ws;
  short* WqkvT = (short*)(ws + OFF_WQKVT);
  short* WoT = (short*)(ws + OFF_WOT);
  short* WgateT = (short*)(ws + OFF_WGATET);
  short* WupT = (short*)(ws + OFF_WUPT);
  short* WdownT = (short*)(ws + OFF_WDOWNT);
  float* biasqkv = (float*)(ws + OFF_BIAS);
  unsigned char* maskb = (unsigned char*)(ws + OFF_MASK);
  float* qm = (float*)(ws + OFF_QM);
  float* km = (float*)(ws + OFF_KM);
  float* qg = (float*)(ws + OFF_QG);
  float* kg = (float*)(ws + OFF_KG);
  float* h2 = (float*)(ws + OFF_H2);
  short* h3_bf = (short*)(ws + OFF_H3);
  short* h_bf = (short*)(ws + OFF_REGA + RA_HBF);
  short* q_bf = (short*)(ws + OFF_REGA + RA_QBF);
  short* k_bf = (short*)(ws + OFF_REGA + RA_KBF);
  short* v_t = (short*)(ws + OFF_REGA + RA_VT);
  short* o_bf = (short*)(ws + OFF_REGA + RA_OBF);
  short* act_bf = (short*)(ws + OFF_REGA);  // overlays h_bf..v_t, all dead by then
  float* qkv_f = (float*)(ws + OFF_REGB);
  float* p0f = (float*)(ws + OFF_REGB);  // overlays qkv_f (dead after rope/vcast)
  float* outp = (float*)d_out;

  dim3 tb(32, 8);
  // weight transposes (fp32 -> bf16, N x K)
  k_transpose_cast<<<dim3(64, 64), tb, 0, stream>>>(Wq, WqkvT, HIDN, 2048);
  k_transpose_cast<<<dim3(16, 64), tb, 0, stream>>>(Wk, WqkvT + (size_t)2048 * HIDN, HIDN, 512);
  k_transpose_cast<<<dim3(16, 64), tb, 0, stream>>>(Wv, WqkvT + (size_t)2560 * HIDN, HIDN, 512);
  k_transpose_cast<<<dim3(64, 64), tb, 0, stream>>>(Wo, WoT, HIDN, HIDN);
  k_transpose_cast<<<dim3(176, 64), tb, 0, stream>>>(Wgate, WgateT, HIDN, INTER);
  k_transpose_cast<<<dim3(176, 64), tb, 0, stream>>>(Wup, WupT, HIDN, INTER);
  k_transpose_cast<<<dim3(64, 176), tb, 0, stream>>>(Wdown, WdownT, INTER, HIDN);
  k_bias_concat<<<12, 256, 0, stream>>>(bq, bk, bv, biasqkv);

  // h = RMS(hidden, ln1) -> bf16
  k_rms<<<S_LEN, 256, 0, stream>>>(hidden, ln1, h_bf);
  // qkv = h @ [Wq|Wk|Wv] + bias  (fp32)  [BN=64: 768 blocks, 3/CU]
  k_gemm<0, 64><<<dim3(NQKV / 64, S_LEN / 128), 256, 0, stream>>>(
      h_bf, WqkvT, qkv_f, nullptr, biasqkv, nullptr, S_LEN, NQKV, HIDN, HIDN);
  // gate path (pre-RoPE q,k)
  k_blockmean<<<320, 256, 0, stream>>>(qkv_f, qm, km);
  k_gateproj<<<640, 128, 0, stream>>>(qm, km, gWq, gWk, qg, kg);
  k_gatemask<<<dim3(32, 16), 64, 0, stream>>>(qg, kg, maskb);
  // RoPE + layout change
  k_rope<<<10240, 256, 0, stream>>>(qkv_f, cosb, sinb, q_bf, k_bf);
  k_vcast_t<<<dim3(4, 64, 4), tb, 0, stream>>>(qkv_f, v_t);
  // attention
  k_attn<<<dim3(32, 16), 256, 0, stream>>>(q_bf, k_bf, v_t, maskb, o_bf);
  // h2 = o @ Wo + hidden (fp32)  [BN=64: 512 blocks, 2/CU]
  k_gemm<0, 64><<<dim3(HIDN / 64, S_LEN / 128), 256, 0, stream>>>(
      o_bf, WoT, h2, nullptr, nullptr, hidden, S_LEN, HIDN, HIDN, HIDN);
  // h3 = RMS(h2, ln2) -> bf16
  k_rms<<<S_LEN, 256, 0, stream>>>(h2, ln2, h3_bf);
  // act = silu(h3 @ Wgate) * (h3 @ Wup)  (fused dual-B, bf16 out)
  k_gemm_gu<<<dim3(INTER / 128, S_LEN / 128), 256, 0, stream>>>(
      h3_bf, WgateT, WupT, act_bf, S_LEN, INTER, HIDN);
  // out partials = act @ Wdown  (split-K x2 in one dispatch: 1024 blocks, 4/CU)
  k_gemm<4, 64><<<dim3(HIDN / 64, S_LEN / 128, 2), 256, 0, stream>>>(
      act_bf, WdownT, p0f, outp, nullptr, nullptr, S_LEN, HIDN, INTER, INTER / 2);
  // out = out + p0 + h2
  k_finish<<<2048, 256, 0, stream>>>(p0f, h2, outp);
  (void)in_sizes; (void)n_in; (void)out_size;
}

// Round 3
// 656.725 us; speedup vs baseline: 1.1157x; 1.0655x over previous
//
#include <hip/hip_runtime.h>
#include <stdint.h>
#include <stddef.h>

// ---------------- problem constants ----------------
#define S_LEN 2048
#define HIDN  2048
#define HQ    16
#define HKV   4
#define HDIM  128
#define NQKV  3072      // HQ*D + 2*HKV*D
#define QBLK  32        // S/64
#define GHW   128
#define INTER 5632
#define NEGF  (-1e30f)
#define THRG  0.004f

typedef short bf16x8 __attribute__((ext_vector_type(8)));
typedef float f32x4  __attribute__((ext_vector_type(4)));

__device__ __forceinline__ short f2bf(float f) {
  union { float f; unsigned u; } v; v.f = f;
  unsigned r = (v.u + 0x7FFFu + ((v.u >> 16) & 1u)) >> 16;
  return (short)r;
}
__device__ __forceinline__ float bf2f(short s) {
  union { float f; unsigned u; } v; v.u = ((unsigned)(unsigned short)s) << 16;
  return v.f;
}
__device__ __forceinline__ void gload16(const void* g, void* l) {
  __builtin_amdgcn_global_load_lds(
      (const __attribute__((address_space(1))) void*)g,
      (__attribute__((address_space(3))) void*)l, 16, 0, 0);
}
// pack two f32 -> [bf16(hi)<<16 | bf16(lo)] via byte-select (truncation)
__device__ __forceinline__ unsigned pack_bf2(float hi, float lo) {
  return __builtin_amdgcn_perm(__float_as_uint(hi), __float_as_uint(lo), 0x07060302u);
}

// ---------------- transpose + cast fp32 (R x C) -> bf16 (C x R) ----------------
__global__ __launch_bounds__(256) void k_transpose_cast(
    const float* __restrict__ src, short* __restrict__ dst, int R, int C) {
  __shared__ float t[32][33];
  const int tx = threadIdx.x, ty = threadIdx.y;
  const int x = blockIdx.x * 32 + tx;
  const int y0 = blockIdx.y * 32;
#pragma unroll
  for (int i = 0; i < 4; i++) {
    int yy = ty + i * 8;
    t[yy][tx] = src[(long)(y0 + yy) * C + x];
  }
  __syncthreads();
  const int xo = blockIdx.y * 32 + tx;
  const int yo0 = blockIdx.x * 32;
#pragma unroll
  for (int i = 0; i < 4; i++) {
    int yy = ty + i * 8;
    dst[(long)(yo0 + yy) * R + xo] = f2bf(t[tx][yy]);
  }
}

// ---------------- concat qkv bias ----------------
__global__ void k_bias_concat(const float* __restrict__ bq, const float* __restrict__ bk,
                              const float* __restrict__ bv, float* __restrict__ out) {
  int i = blockIdx.x * 256 + threadIdx.x;
  if (i < 2048) out[i] = bq[i];
  else if (i < 2560) out[i] = bk[i - 2048];
  else out[i] = bv[i - 2560];
}

// ---------------- RMSNorm fp32 -> bf16 ----------------
__global__ __launch_bounds__(256) void k_rms(const float* __restrict__ x,
                                             const float* __restrict__ w,
                                             short* __restrict__ out) {
  const int row = blockIdx.x;
  const float* xr = x + (long)row * HIDN;
  float v[8];
  float ss = 0.f;
#pragma unroll
  for (int i = 0; i < 8; i++) {
    v[i] = xr[threadIdx.x + i * 256];
    ss += v[i] * v[i];
  }
#pragma unroll
  for (int off = 32; off > 0; off >>= 1) ss += __shfl_down(ss, off, 64);
  __shared__ float red[4];
  const int wave = threadIdx.x >> 6, lane = threadIdx.x & 63;
  if (lane == 0) red[wave] = ss;
  __syncthreads();
  float tot = red[0] + red[1] + red[2] + red[3];
  float rs = rsqrtf(tot / (float)HIDN + 1e-6f);
#pragma unroll
  for (int i = 0; i < 8; i++) {
    int c = threadIdx.x + i * 256;
    out[(long)row * HIDN + c] = f2bf(v[i] * rs * w[c]);
  }
}

// ---------------- fused split-K reduce + RMSNorm ----------------
// h2 = p0 + h2(partial1) + hid ; out = bf16(rms(h2) * w)
__global__ __launch_bounds__(256) void k_rms_fin(const float* __restrict__ p0,
                                                 const float* __restrict__ hid,
                                                 const float* __restrict__ w,
                                                 float* __restrict__ h2,
                                                 short* __restrict__ out) {
  const int row = blockIdx.x;
  const long base = (long)row * HIDN;
  float v[8];
  float ss = 0.f;
#pragma unroll
  for (int i = 0; i < 8; i++) {
    int c = threadIdx.x + i * 256;
    float t = p0[base + c] + h2[base + c] + hid[base + c];
    h2[base + c] = t;
    v[i] = t;
    ss += t * t;
  }
#pragma unroll
  for (int off = 32; off > 0; off >>= 1) ss += __shfl_down(ss, off, 64);
  __shared__ float red[4];
  const int wave = threadIdx.x >> 6, lane = threadIdx.x & 63;
  if (lane == 0) red[wave] = ss;
  __syncthreads();
  float tot = red[0] + red[1] + red[2] + red[3];
  float rs = rsqrtf(tot / (float)HIDN + 1e-6f);
#pragma unroll
  for (int i = 0; i < 8; i++) {
    int c = threadIdx.x + i * 256;
    out[base + c] = f2bf(v[i] * rs * w[c]);
  }
}

// ---------------- GEMM: C[M,N] = A[M,K](bf16) * Bt[N,K](bf16)^T  ----------------
// MODE 0: Cf = acc + bias? + add?   (fp32 out)
// MODE 1: Cb = bf16(acc)
// MODE 2: Cb = bf16(silu(gaux) * acc)
// MODE 4: split-K partial: z==0 -> Cf, z==1 -> Cf2 (no bias/add)
// BK=64: tiles stored as two k-half panels [2][rows][32].
// ksl = K-slice length per z (== K when gridDim.z == 1).
template <int MODE, int BN>
__global__ __launch_bounds__(256) void k_gemm(
    const short* __restrict__ A, const short* __restrict__ Bt,
    float* __restrict__ Cf, float* __restrict__ Cf2, short* __restrict__ Cb,
    const float* __restrict__ bias, const float* __restrict__ add,
    const short* __restrict__ gaux, int M, int N, int K, int ksl) {
  constexpr int NT = BN / 32;   // n-tiles per wave
  constexpr int BIW = BN / 32;  // per-wave B staging instrs
  constexpr int BPP = BN / 16;  // B staging instrs per k-half panel
  __shared__ short As[2][128][32];
  __shared__ short Bs[2][BN][32];
  const int tid = threadIdx.x;
  const int wave = tid >> 6, lane = tid & 63, quad = lane >> 4, l15 = lane & 15;
  const long m0 = (long)blockIdx.y * 128, n0 = (long)blockIdx.x * BN;
  const int wr = (wave >> 1) * 64, wc = (wave & 1) * (BN / 2);
  const int i2 = lane >> 2, i3 = lane & 3;
  f32x4 acc[4][NT] = {};
  // A staging: 16 instrs (4/wave). instr g: k-half h=g>>3, rows (g&7)*16..+15
  const short* Ainst[4];
  short* Alds[4];
#pragma unroll
  for (int j = 0; j < 4; j++) {
    const int g = wave * 4 + j, h = g >> 3, rb = (g & 7) * 16;
    Ainst[j] = A + (m0 + rb + i2) * K + h * 32 + i3 * 8;
    Alds[j] = &As[h][rb][0];
  }
  // B staging: BN/8 instrs (BIW/wave)
  const short* Binst[BIW];
  short* Blds[BIW];
#pragma unroll
  for (int j = 0; j < BIW; j++) {
    const int g = wave * BIW + j, h = g / BPP, rb = (g % BPP) * 16;
    Binst[j] = Bt + (n0 + rb + i2) * K + h * 32 + i3 * 8;
    Blds[j] = &Bs[h][rb][0];
  }
  const int kbeg = (MODE == 4) ? blockIdx.z * ksl : 0;
  const int kend = kbeg + ((MODE == 4) ? ksl : K);
  for (int k0 = kbeg; k0 < kend; k0 += 64) {
    __syncthreads();
#pragma unroll
    for (int j = 0; j < 4; j++) gload16(Ainst[j] + k0, Alds[j]);
#pragma unroll
    for (int j = 0; j < BIW; j++) gload16(Binst[j] + k0, Blds[j]);
    __syncthreads();
#pragma unroll
    for (int s = 0; s < 2; s++) {
      bf16x8 af[4], bb[NT];
#pragma unroll
      for (int mi = 0; mi < 4; mi++)
        af[mi] = *(const bf16x8*)&As[s][wr + mi * 16 + l15][quad * 8];
#pragma unroll
      for (int ni = 0; ni < NT; ni++)
        bb[ni] = *(const bf16x8*)&Bs[s][wc + ni * 16 + l15][quad * 8];
#pragma unroll
      for (int mi = 0; mi < 4; mi++)
#pragma unroll
        for (int ni = 0; ni < NT; ni++)
          acc[mi][ni] = __builtin_amdgcn_mfma_f32_16x16x32_bf16(af[mi], bb[ni], acc[mi][ni], 0, 0, 0);
    }
  }
  const bool hb = (MODE == 0) && (bias != nullptr);
  const bool ha = (MODE == 0) && (add != nullptr);
  float* dstp = (MODE == 4) ? ((blockIdx.z == 0) ? Cf : Cf2) : Cf;
#pragma unroll
  for (int mi = 0; mi < 4; mi++) {
#pragma unroll
    for (int ni = 0; ni < NT; ni++) {
      long mbase = m0 + wr + mi * 16 + quad * 4;
      long n = n0 + wc + ni * 16 + l15;
#pragma unroll
      for (int r = 0; r < 4; r++) {
        float v = acc[mi][ni][r];
        long idx = (mbase + r) * N + n;
        if (MODE == 0) {
          if (hb) v += bias[n];
          if (ha) v += add[idx];
          Cf[idx] = v;
        } else if (MODE == 1) {
          Cb[idx] = f2bf(v);
        } else if (MODE == 2) {
          float g = bf2f(gaux[idx]);
          float sg = g / (1.f + __expf(-g));
          Cb[idx] = f2bf(sg * v);
        } else {
          dstp[idx] = v;
        }
      }
    }
  }
}

// ---------------- final reduce: out = out(partial1) + p0 + h2 ----------------
__global__ __launch_bounds__(256) void k_finish(const float* __restrict__ p0,
                                                const float* __restrict__ h2,
                                                float* __restrict__ out) {
  const long n = (long)S_LEN * HIDN;
  for (long i = ((long)blockIdx.x * 256 + threadIdx.x) * 4; i < n;
       i += (long)gridDim.x * 256 * 4) {
    float4 a = *(const float4*)(out + i);
    float4 b = *(const float4*)(p0 + i);
    float4 c = *(const float4*)(h2 + i);
    a.x += b.x + c.x;
    a.y += b.y + c.y;
    a.z += b.z + c.z;
    a.w += b.w + c.w;
    *(float4*)(out + i) = a;
  }
}

// ---------------- block means of q and k (pre-RoPE) ----------------
__global__ __launch_bounds__(256) void k_blockmean(const float* __restrict__ qkv,
                                                   float* __restrict__ qm,
                                                   float* __restrict__ km) {
  int id = blockIdx.x * 256 + threadIdx.x;  // 32 * 2560
  int qb = id / 2560, c = id % 2560;        // cols 0..2559 = q(2048) + k(512)
  const float* base = qkv + (long)qb * 64 * NQKV + c;
  float acc = 0.f;
  for (int s = 0; s < 64; s++) acc += base[(long)s * NQKV];
  acc *= (1.f / 64.f);
  if (c < 2048) qm[(long)qb * 2048 + c] = acc;
  else km[(long)qb * 512 + (c - 2048)] = acc;
}

// ---------------- gate projections qg = qm@gWq, kg = km@gWk ----------------
__global__ __launch_bounds__(128) void k_gateproj(const float* __restrict__ qm,
                                                  const float* __restrict__ km,
                                                  const float* __restrict__ gWq,
                                                  const float* __restrict__ gWk,
                                                  float* __restrict__ qg,
                                                  float* __restrict__ kg) {
  __shared__ float xm[128];
  const int b = blockIdx.x;
  const float* src; const float* W; float* dst;
  if (b < 512) { src = qm + (long)b * 128; W = gWq; dst = qg + (long)b * 128; }
  else { int r = b - 512; src = km + (long)r * 128; W = gWk; dst = kg + (long)r * 128; }
  xm[threadIdx.x] = src[threadIdx.x];
  __syncthreads();
  float acc = 0.f;
  for (int d = 0; d < 128; d++) acc += xm[d] * W[d * GHW + threadIdx.x];
  dst[threadIdx.x] = acc;
}

// ---------------- gate softmax + keep mask ----------------
__global__ __launch_bounds__(64) void k_gatemask(const float* __restrict__ qg,
                                                 const float* __restrict__ kg,
                                                 unsigned char* __restrict__ mask) {
  const int qb = blockIdx.x, h = blockIdx.y;
  __shared__ float qv[128];
  const int t = threadIdx.x;
  qv[t] = qg[((long)qb * 16 + h) * 128 + t];
  qv[t + 64] = qg[((long)qb * 16 + h) * 128 + t + 64];
  __syncthreads();
  const int kb = t;
  float s = NEGF;
  if (kb < 32 && kb <= qb) {
    const float* kr = kg + ((long)kb * 4 + (h >> 2)) * 128;
    float acc = 0.f;
    for (int d = 0; d < 128; d++) acc += qv[d] * kr[d];
    s = acc * 0.08838834764831845f;  // GH^-0.5
  }
  float m = s;
#pragma unroll
  for (int off = 32; off > 0; off >>= 1) m = fmaxf(m, __shfl_xor(m, off, 64));
  float e = (kb < 32 && kb <= qb) ? __expf(s - m) : 0.f;
  float sum = e;
#pragma unroll
  for (int off = 32; off > 0; off >>= 1) sum += __shfl_xor(sum, off, 64);
  if (kb < 32) {
    float gate = e / sum;
    bool keep = (kb <= qb) && (gate >= THRG || kb == qb);
    mask[((long)h * 32 + qb) * 32 + kb] = keep ? 1 : 0;
  }
}

// ---------------- RoPE + cast q,k -> head-major bf16 ----------------
__global__ __launch_bounds__(256) void k_rope(const float* __restrict__ qkv,
                                              const float* __restrict__ cosb,
                                              const float* __restrict__ sinb,
                                              short* __restrict__ q_bf,
                                              short* __restrict__ k_bf) {
  long id = (long)blockIdx.x * 256 + threadIdx.x;  // S * 20 * 64
  int d = (int)(id & 63);
  long rest = id >> 6;
  int head = (int)(rest % 20);
  int s = (int)(rest / 20);
  const float c = cosb[(long)s * HDIM + d];
  const float sn = sinb[(long)s * HDIM + d];
  if (head < HQ) {
    const float* src = qkv + (long)s * NQKV + head * HDIM;
    float x1 = src[d], x2 = src[d + 64];
    short* dst = q_bf + ((long)head * S_LEN + s) * HDIM;
    dst[d] = f2bf(x1 * c - x2 * sn);
    dst[d + 64] = f2bf(x2 * c + x1 * sn);
  } else {
    int hk = head - HQ;
    const float* src = qkv + (long)s * NQKV + 2048 + hk * HDIM;
    float x1 = src[d], x2 = src[d + 64];
    short* dst = k_bf + ((long)hk * S_LEN + s) * HDIM;
    dst[d] = f2bf(x1 * c - x2 * sn);
    dst[d + 64] = f2bf(x2 * c + x1 * sn);
  }
}

// ---------------- v transpose-cast (tiled, coalesced): v_t[hk][d][s] ----------------
__global__ __launch_bounds__(256) void k_vcast_t(const float* __restrict__ qkv,
                                                 short* __restrict__ v_t) {
  __shared__ float t[32][33];
  const int hk = blockIdx.z;
  const int tx = threadIdx.x, ty = threadIdx.y;  // 32 x 8
  const int d0 = blockIdx.x * 32;                // within HDIM
  const int s0 = blockIdx.y * 32;                // within S
  const float* src = qkv + 2560 + (long)hk * HDIM;
#pragma unroll
  for (int i = 0; i < 4; i++) {
    int s = ty + i * 8;
    t[s][tx] = src[(long)(s0 + s) * NQKV + d0 + tx];
  }
  __syncthreads();
  short* dst = v_t + (long)hk * HDIM * S_LEN;
#pragma unroll
  for (int i = 0; i < 4; i++) {
    int d = ty + i * 8;
    dst[(long)(d0 + d) * S_LEN + s0 + tx] = f2bf(t[tx][d]);
  }
}

// ---------------- flash attention: LDS staging + S^T register softmax ----------------
__global__ __launch_bounds__(256) void k_attn(const short* __restrict__ q_bf,
                                              const short* __restrict__ k_bf,
                                              const short* __restrict__ v_t,
                                              const unsigned char* __restrict__ mask,
                                              short* __restrict__ o_bf) {
  const int qb = blockIdx.x, h = blockIdx.y;
  const int tid = threadIdx.x, wave = tid >> 6, lane = tid & 63;
  const int quad = lane >> 4, l15 = lane & 15;
  __shared__ short Ks[4 * 64 * 32];   // panel kd: [row r][32]
  __shared__ short Vs[2 * 128 * 32];  // panel ksb: [d][32]
  __shared__ short Ps[4][16 * 72];    // per-wave P, padded stride 72 shorts
  short* Pw = Ps[wave];
  const int hk = h >> 2;
  const unsigned char* mptr = mask + ((long)h * 32 + qb) * 32;
  const float SCL = 0.08838834764831845f * 1.4426950408889634f;  // D^-.5 * log2e
  const int qrow_g = qb * 64 + wave * 16 + l15;  // this lane's q-row

  // Q B-frags (n = q-row indexed by l15), resident all kernel
  bf16x8 bq[4];
  {
    const short* qrp = q_bf + ((long)h * S_LEN + qrow_g) * HDIM + quad * 8;
#pragma unroll
    for (int kd = 0; kd < 4; kd++) bq[kd] = *(const bf16x8*)(qrp + kd * 32);
  }

  const short* kh = k_bf + (long)hk * S_LEN * HDIM;
  const short* vh = v_t + (long)hk * HDIM * S_LEN;

  const int i2 = lane >> 2, i3 = lane & 3;
  int koff[4], voff[4];
  const int vp = wave >> 1, vhh = wave & 1;
#pragma unroll
  for (int inst = 0; inst < 4; inst++) {
    koff[inst] = (inst * 16 + i2) * HDIM + wave * 32 + i3 * 8;
    voff[inst] = (vhh * 64 + inst * 16 + i2) * S_LEN + vp * 32 + i3 * 8;
  }

  f32x4 accO[8] = {};
  float mrow = -3.0e38f, lrow = 0.f;

  for (int kb = 0; kb <= qb; kb++) {
    if (!mptr[kb]) continue;  // block-uniform
    __syncthreads();  // prior iter's LDS reads done before overwrite
    {
      const int kg = kb * 64 * HDIM;
      const int vg = kb * 64;
#pragma unroll
      for (int inst = 0; inst < 4; inst++) {
        gload16(kh + kg + koff[inst], &Ks[wave * 2048 + inst * 512]);
        gload16(vh + vg + voff[inst], &Vs[vp * 4096 + (vhh * 64 + inst * 16) * 32]);
      }
    }
    __syncthreads();  // all staging landed (compiler drains vmcnt)

    // ---- S^T: 4 subtiles; lane ends with 16 scores for its q-row ----
    f32x4 sv[4];
#pragma unroll
    for (int nt = 0; nt < 4; nt++) {
      f32x4 t = {};
#pragma unroll
      for (int kd = 0; kd < 4; kd++) {
        bf16x8 ka = *(const bf16x8*)&Ks[kd * 2048 + (nt * 16 + l15) * 32 + quad * 8];
        t = __builtin_amdgcn_mfma_f32_16x16x32_bf16(ka, bq[kd], t, 0, 0, 0);
      }
      sv[nt] = t;
    }
    // ---- scale + mask + row max ----
    float lmx = -__builtin_inff();
    if (kb < qb) {
#pragma unroll
      for (int nt = 0; nt < 4; nt++)
#pragma unroll
        for (int r = 0; r < 4; r++) {
          sv[nt][r] *= SCL;
          lmx = fmaxf(lmx, sv[nt][r]);
        }
    } else {  // diagonal block
#pragma unroll
      for (int nt = 0; nt < 4; nt++)
#pragma unroll
        for (int r = 0; r < 4; r++) {
          const int kcol = kb * 64 + nt * 16 + quad * 4 + r;
          sv[nt][r] = (kcol <= qrow_g) ? sv[nt][r] * SCL : -__builtin_inff();
          lmx = fmaxf(lmx, sv[nt][r]);
        }
    }
    lmx = fmaxf(lmx, __shfl_xor(lmx, 16, 64));
    lmx = fmaxf(lmx, __shfl_xor(lmx, 32, 64));
    const float mnew = fmaxf(mrow, lmx);
    const float alpha = __builtin_amdgcn_exp2f(mrow - mnew);
    mrow = mnew;
    // ---- exp2 + sum + packed P write (padded stride, b64) ----
    float psum = 0.f;
#pragma unroll
    for (int nt = 0; nt < 4; nt++) {
#pragma unroll
      for (int r = 0; r < 4; r++) {
        float p = __builtin_amdgcn_exp2f(sv[nt][r] - mnew);
        sv[nt][r] = p;
        psum += p;
      }
      uint2 u;
      u.x = pack_bf2(sv[nt][1], sv[nt][0]);
      u.y = pack_bf2(sv[nt][3], sv[nt][2]);
      *(uint2*)&Pw[l15 * 72 + nt * 16 + quad * 4] = u;
    }
    psum += __shfl_xor(psum, 16, 64);
    psum += __shfl_xor(psum, 32, 64);
    lrow = lrow * alpha + psum;
    // ---- rescale accO (alpha broadcast: lane j<16 holds row j's alpha) ----
    float al[4];
#pragma unroll
    for (int r = 0; r < 4; r++) al[r] = __shfl(alpha, quad * 4 + r, 64);
#pragma unroll
    for (int dt = 0; dt < 8; dt++)
#pragma unroll
      for (int r = 0; r < 4; r++) accO[dt][r] *= al[r];
    // drain this wave's P writes before fragment reads (per-wave buffer)
    asm volatile("s_waitcnt lgkmcnt(0)" ::: "memory");
    // ---- PV: P(16x64) @ V^T panels ----
    bf16x8 pf[2];
#pragma unroll
    for (int ksb = 0; ksb < 2; ksb++)
      pf[ksb] = *(const bf16x8*)&Pw[l15 * 72 + ksb * 32 + quad * 8];
#pragma unroll
    for (int dt = 0; dt < 8; dt++) {
#pragma unroll
      for (int ksb = 0; ksb < 2; ksb++) {
        bf16x8 vf = *(const bf16x8*)&Vs[ksb * 4096 + (dt * 16 + l15) * 32 + quad * 8];
        accO[dt] = __builtin_amdgcn_mfma_f32_16x16x32_bf16(pf[ksb], vf, accO[dt], 0, 0, 0);
      }
    }
  }
  // ---- epilogue: normalize by l (broadcast like alpha) and store ----
  const float linv = 1.f / lrow;
  float li[4];
#pragma unroll
  for (int r = 0; r < 4; r++) li[r] = __shfl(linv, quad * 4 + r, 64);
#pragma unroll
  for (int r = 0; r < 4; r++) {
    const long srow = (long)qb * 64 + wave * 16 + quad * 4 + r;
#pragma unroll
    for (int dt = 0; dt < 8; dt++)
      o_bf[srow * HIDN + h * HDIM + dt * 16 + l15] = f2bf(accO[dt][r] * li[r]);
  }
}

// ---------------- workspace layout ----------------
static constexpr size_t SZ_WQKVT = (size_t)NQKV * HIDN * 2;
static constexpr size_t SZ_WOT = (size_t)HIDN * HIDN * 2;
static constexpr size_t SZ_WBIG = (size_t)INTER * HIDN * 2;
static constexpr size_t OFF_WQKVT = 0;
static constexpr size_t OFF_WOT = OFF_WQKVT + SZ_WQKVT;
static constexpr size_t OFF_WGATET = OFF_WOT + SZ_WOT;
static constexpr size_t OFF_WUPT = OFF_WGATET + SZ_WBIG;
static constexpr size_t OFF_WDOWNT = OFF_WUPT + SZ_WBIG;
static constexpr size_t OFF_BIAS = OFF_WDOWNT + SZ_WBIG;
static constexpr size_t OFF_MASK = OFF_BIAS + 3072 * 4 + 4096;
static constexpr size_t OFF_QM = OFF_MASK + 16 * 32 * 32 + 4096;
static constexpr size_t OFF_KM = OFF_QM + (size_t)32 * 16 * 128 * 4;
static constexpr size_t OFF_QG = OFF_KM + (size_t)32 * 4 * 128 * 4;
static constexpr size_t OFF_KG = OFF_QG + (size_t)32 * 16 * 128 * 4;
static constexpr size_t OFF_H2 = OFF_KG + (size_t)32 * 4 * 128 * 4;
static constexpr size_t OFF_H3 = OFF_H2 + (size_t)S_LEN * HIDN * 4;
static constexpr size_t OFF_REGA = OFF_H3 + (size_t)S_LEN * HIDN * 2;
//   REGA phase1: h_bf | q_bf | k_bf | v_t | o_bf ; phase2: act_bf (o_bf dead)
static constexpr size_t RA_HBF = 0;
static constexpr size_t RA_QBF = RA_HBF + (size_t)S_LEN * HIDN * 2;
static constexpr size_t RA_KBF = RA_QBF + (size_t)HQ * S_LEN * HDIM * 2;
static constexpr size_t RA_VT = RA_KBF + (size_t)HKV * S_LEN * HDIM * 2;
static constexpr size_t RA_OBF = RA_VT + (size_t)HKV * HDIM * S_LEN * 2;
static constexpr size_t SZ_REGA = RA_OBF + (size_t)S_LEN * HIDN * 2;
static constexpr size_t OFF_REGB = OFF_REGA + SZ_REGA;
//   REGB timeline: qkv_f32 (S x 3072 f32) -> Wo split-K p0 (S x HIDN f32)
//                  -> g_bf (S x INTER bf16) -> Wdown split-K p0. All sequential.
static constexpr size_t SZ_REGB = (size_t)S_LEN * NQKV * 4;
static constexpr size_t TOTAL_WS = OFF_REGB + SZ_REGB;

extern "C" void kernel_launch(void* const* d_in, const int* in_sizes, int n_in,
                              void* d_out, int out_size, void* d_ws, size_t ws_size,
                              hipStream_t stream) {
  const float* hidden = (const float*)d_in[0];
  const float* cosb = (const float*)d_in[1];
  const float* sinb = (const float*)d_in[2];
  const float* ln1 = (const float*)d_in[3];
  const float* ln2 = (const float*)d_in[4];
  const float* Wq = (const float*)d_in[5];
  const float* bq = (const float*)d_in[6];
  const float* Wk = (const float*)d_in[7];
  const float* bk = (const float*)d_in[8];
  const float* Wv = (const float*)d_in[9];
  const float* bv = (const float*)d_in[10];
  const float* Wo = (const float*)d_in[11];
  const float* gWq = (const float*)d_in[12];
  const float* gWk = (const float*)d_in[13];
  const float* Wgate = (const float*)d_in[14];
  const float* Wup = (const float*)d_in[15];
  const float* Wdown = (const float*)d_in[16];

  if (ws_size < TOTAL_WS) return;  // workspace too small; fail visibly

  char* ws = (char*)d_ws;
  short* WqkvT = (short*)(ws + OFF_WQKVT);
  short* WoT = (short*)(ws + OFF_WOT);
  short* WgateT = (short*)(ws + OFF_WGATET);
  short* WupT = (short*)(ws + OFF_WUPT);
  short* WdownT = (short*)(ws + OFF_WDOWNT);
  float* biasqkv = (float*)(ws + OFF_BIAS);
  unsigned char* maskb = (unsigned char*)(ws + OFF_MASK);
  float* qm = (float*)(ws + OFF_QM);
  float* km = (float*)(ws + OFF_KM);
  float* qg = (float*)(ws + OFF_QG);
  float* kg = (float*)(ws + OFF_KG);
  float* h2 = (float*)(ws + OFF_H2);
  short* h3_bf = (short*)(ws + OFF_H3);
  short* h_bf = (short*)(ws + OFF_REGA + RA_HBF);
  short* q_bf = (short*)(ws + OFF_REGA + RA_QBF);
  short* k_bf = (short*)(ws + OFF_REGA + RA_KBF);
  short* v_t = (short*)(ws + OFF_REGA + RA_VT);
  short* o_bf = (short*)(ws + OFF_REGA + RA_OBF);
  short* act_bf = (short*)(ws + OFF_REGA);  // overlays h_bf..v_t, all dead by then
  float* qkv_f = (float*)(ws + OFF_REGB);
  float* p0f = (float*)(ws + OFF_REGB);   // split-K partial0 (sequential reuse)
  short* g_bf = (short*)(ws + OFF_REGB);  // gate output (sequential reuse)
  float* outp = (float*)d_out;

  dim3 tb(32, 8);
  // weight transposes (fp32 -> bf16, N x K)
  k_transpose_cast<<<dim3(64, 64), tb, 0, stream>>>(Wq, WqkvT, HIDN, 2048);
  k_transpose_cast<<<dim3(16, 64), tb, 0, stream>>>(Wk, WqkvT + (size_t)2048 * HIDN, HIDN, 512);
  k_transpose_cast<<<dim3(16, 64), tb, 0, stream>>>(Wv, WqkvT + (size_t)2560 * HIDN, HIDN, 512);
  k_transpose_cast<<<dim3(64, 64), tb, 0, stream>>>(Wo, WoT, HIDN, HIDN);
  k_transpose_cast<<<dim3(176, 64), tb, 0, stream>>>(Wgate, WgateT, HIDN, INTER);
  k_transpose_cast<<<dim3(176, 64), tb, 0, stream>>>(Wup, WupT, HIDN, INTER);
  k_transpose_cast<<<dim3(64, 176), tb, 0, stream>>>(Wdown, WdownT, INTER, HIDN);
  k_bias_concat<<<12, 256, 0, stream>>>(bq, bk, bv, biasqkv);

  // h = RMS(hidden, ln1) -> bf16
  k_rms<<<S_LEN, 256, 0, stream>>>(hidden, ln1, h_bf);
  // qkv = h @ [Wq|Wk|Wv] + bias  (fp32)  [BN=64: 768 blocks, 3/CU]
  k_gemm<0, 64><<<dim3(NQKV / 64, S_LEN / 128), 256, 0, stream>>>(
      h_bf, WqkvT, qkv_f, nullptr, nullptr, biasqkv, nullptr, nullptr, S_LEN, NQKV, HIDN, HIDN);
  // gate path (pre-RoPE q,k)
  k_blockmean<<<320, 256, 0, stream>>>(qkv_f, qm, km);
  k_gateproj<<<640, 128, 0, stream>>>(qm, km, gWq, gWk, qg, kg);
  k_gatemask<<<dim3(32, 16), 64, 0, stream>>>(qg, kg, maskb);
  // RoPE + layout change
  k_rope<<<10240, 256, 0, stream>>>(qkv_f, cosb, sinb, q_bf, k_bf);
  k_vcast_t<<<dim3(4, 64, 4), tb, 0, stream>>>(qkv_f, v_t);
  // attention
  k_attn<<<dim3(32, 16), 256, 0, stream>>>(q_bf, k_bf, v_t, maskb, o_bf);
  // Wo partials = o @ Wo  (split-K x2: 1024 blocks, 4/CU; reduce fused into rms)
  k_gemm<4, 64><<<dim3(HIDN / 64, S_LEN / 128, 2), 256, 0, stream>>>(
      o_bf, WoT, p0f, h2, nullptr, nullptr, nullptr, nullptr, S_LEN, HIDN, HIDN, HIDN / 2);
  // h2 = p0 + p1 + hidden ; h3 = RMS(h2, ln2) -> bf16
  k_rms_fin<<<S_LEN, 256, 0, stream>>>(p0f, hidden, ln2, h2, h3_bf);
  // g = h3 @ Wgate (bf16)
  k_gemm<1, 128><<<dim3(INTER / 128, S_LEN / 128), 256, 0, stream>>>(
      h3_bf, WgateT, nullptr, nullptr, g_bf, nullptr, nullptr, nullptr, S_LEN, INTER, HIDN, HIDN);
  // act = silu(g) * (h3 @ Wup) (bf16)
  k_gemm<2, 128><<<dim3(INTER / 128, S_LEN / 128), 256, 0, stream>>>(
      h3_bf, WupT, nullptr, nullptr, act_bf, nullptr, nullptr, g_bf, S_LEN, INTER, HIDN, HIDN);
  // out partials = act @ Wdown  (split-K x2: 1024 blocks, 4/CU)
  k_gemm<4, 64><<<dim3(HIDN / 64, S_LEN / 128, 2), 256, 0, stream>>>(
      act_bf, WdownT, p0f, outp, nullptr, nullptr, nullptr, nullptr, S_LEN, HIDN, INTER, INTER / 2);
  // out = out + p0 + h2
  k_finish<<<2048, 256, 0, stream>>>(p0f, h2, outp);
  (void)in_sizes; (void)n_in; (void)out_size;
}

// Round 4
// 636.703 us; speedup vs baseline: 1.1507x; 1.0314x over previous
//
#include <hip/hip_runtime.h>
#include <stdint.h>
#include <stddef.h>

// ---------------- problem constants ----------------
#define S_LEN 2048
#define HIDN  2048
#define HQ    16
#define HKV   4
#define HDIM  128
#define NQKV  3072      // HQ*D + 2*HKV*D
#define QBLK  32        // S/64
#define GHW   128
#define INTER 5632
#define NEGF  (-1e30f)
#define THRG  0.004f

typedef short bf16x8 __attribute__((ext_vector_type(8)));
typedef float f32x4  __attribute__((ext_vector_type(4)));

__device__ __forceinline__ short f2bf(float f) {
  union { float f; unsigned u; } v; v.f = f;
  unsigned r = (v.u + 0x7FFFu + ((v.u >> 16) & 1u)) >> 16;
  return (short)r;
}
__device__ __forceinline__ float bf2f(short s) {
  union { float f; unsigned u; } v; v.u = ((unsigned)(unsigned short)s) << 16;
  return v.f;
}
__device__ __forceinline__ void gload16(const void* g, void* l) {
  __builtin_amdgcn_global_load_lds(
      (const __attribute__((address_space(1))) void*)g,
      (__attribute__((address_space(3))) void*)l, 16, 0, 0);
}
// pack two f32 -> [bf16(hi)<<16 | bf16(lo)] via byte-select (truncation)
__device__ __forceinline__ unsigned pack_bf2(float hi, float lo) {
  return __builtin_amdgcn_perm(__float_as_uint(hi), __float_as_uint(lo), 0x07060302u);
}

// ---------------- transpose + cast fp32 (R x C) -> bf16 (C x R) ----------------
__global__ __launch_bounds__(256) void k_transpose_cast(
    const float* __restrict__ src, short* __restrict__ dst, int R, int C) {
  __shared__ float t[32][33];
  const int tx = threadIdx.x, ty = threadIdx.y;
  const int x = blockIdx.x * 32 + tx;
  const int y0 = blockIdx.y * 32;
#pragma unroll
  for (int i = 0; i < 4; i++) {
    int yy = ty + i * 8;
    t[yy][tx] = src[(long)(y0 + yy) * C + x];
  }
  __syncthreads();
  const int xo = blockIdx.y * 32 + tx;
  const int yo0 = blockIdx.x * 32;
#pragma unroll
  for (int i = 0; i < 4; i++) {
    int yy = ty + i * 8;
    dst[(long)(yo0 + yy) * R + xo] = f2bf(t[tx][yy]);
  }
}

// ---------------- concat qkv bias ----------------
__global__ void k_bias_concat(const float* __restrict__ bq, const float* __restrict__ bk,
                              const float* __restrict__ bv, float* __restrict__ out) {
  int i = blockIdx.x * 256 + threadIdx.x;
  if (i < 2048) out[i] = bq[i];
  else if (i < 2560) out[i] = bk[i - 2048];
  else out[i] = bv[i - 2560];
}

// ---------------- RMSNorm fp32 -> bf16 ----------------
__global__ __launch_bounds__(256) void k_rms(const float* __restrict__ x,
                                             const float* __restrict__ w,
                                             short* __restrict__ out) {
  const int row = blockIdx.x;
  const float* xr = x + (long)row * HIDN;
  float v[8];
  float ss = 0.f;
#pragma unroll
  for (int i = 0; i < 8; i++) {
    v[i] = xr[threadIdx.x + i * 256];
    ss += v[i] * v[i];
  }
#pragma unroll
  for (int off = 32; off > 0; off >>= 1) ss += __shfl_down(ss, off, 64);
  __shared__ float red[4];
  const int wave = threadIdx.x >> 6, lane = threadIdx.x & 63;
  if (lane == 0) red[wave] = ss;
  __syncthreads();
  float tot = red[0] + red[1] + red[2] + red[3];
  float rs = rsqrtf(tot / (float)HIDN + 1e-6f);
#pragma unroll
  for (int i = 0; i < 8; i++) {
    int c = threadIdx.x + i * 256;
    out[(long)row * HIDN + c] = f2bf(v[i] * rs * w[c]);
  }
}

// ---------------- fused split-K reduce + RMSNorm ----------------
// h2 = p0 + h2(partial1) + hid ; out = bf16(rms(h2) * w)
__global__ __launch_bounds__(256) void k_rms_fin(const float* __restrict__ p0,
                                                 const float* __restrict__ hid,
                                                 const float* __restrict__ w,
                                                 float* __restrict__ h2,
                                                 short* __restrict__ out) {
  const int row = blockIdx.x;
  const long base = (long)row * HIDN;
  float v[8];
  float ss = 0.f;
#pragma unroll
  for (int i = 0; i < 8; i++) {
    int c = threadIdx.x + i * 256;
    float t = p0[base + c] + h2[base + c] + hid[base + c];
    h2[base + c] = t;
    v[i] = t;
    ss += t * t;
  }
#pragma unroll
  for (int off = 32; off > 0; off >>= 1) ss += __shfl_down(ss, off, 64);
  __shared__ float red[4];
  const int wave = threadIdx.x >> 6, lane = threadIdx.x & 63;
  if (lane == 0) red[wave] = ss;
  __syncthreads();
  float tot = red[0] + red[1] + red[2] + red[3];
  float rs = rsqrtf(tot / (float)HIDN + 1e-6f);
#pragma unroll
  for (int i = 0; i < 8; i++) {
    int c = threadIdx.x + i * 256;
    out[base + c] = f2bf(v[i] * rs * w[c]);
  }
}

// ---------------- GEMM: C[M,N] = A[M,K](bf16) * Bt[N,K](bf16)^T  ----------------
// MODE 0: Cf = acc + bias? + add?   (fp32 out)
// MODE 3: dual bf16 dest: n<INTER -> Cb, n>=INTER -> Cb2 (row stride INTER)
// MODE 4: split-K partial: z==0 -> Cf, z==1 -> Cf2 (no bias/add)
// BK=64: tiles stored as two k-half panels [2][rows][32].
// ksl = K-slice length per z (== K when gridDim.z == 1).
template <int MODE, int BN>
__global__ __launch_bounds__(256) void k_gemm(
    const short* __restrict__ A, const short* __restrict__ Bt,
    float* __restrict__ Cf, float* __restrict__ Cf2,
    short* __restrict__ Cb, short* __restrict__ Cb2,
    const float* __restrict__ bias, const float* __restrict__ add,
    int M, int N, int K, int ksl) {
  constexpr int NT = BN / 32;   // n-tiles per wave
  constexpr int BIW = BN / 32;  // per-wave B staging instrs
  constexpr int BPP = BN / 16;  // B staging instrs per k-half panel
  __shared__ short As[2][128][32];
  __shared__ short Bs[2][BN][32];
  const int tid = threadIdx.x;
  const int wave = tid >> 6, lane = tid & 63, quad = lane >> 4, l15 = lane & 15;
  const long m0 = (long)blockIdx.y * 128, n0 = (long)blockIdx.x * BN;
  const int wr = (wave >> 1) * 64, wc = (wave & 1) * (BN / 2);
  const int i2 = lane >> 2, i3 = lane & 3;
  f32x4 acc[4][NT] = {};
  // A staging: 16 instrs (4/wave). instr g: k-half h=g>>3, rows (g&7)*16..+15
  const short* Ainst[4];
  short* Alds[4];
#pragma unroll
  for (int j = 0; j < 4; j++) {
    const int g = wave * 4 + j, h = g >> 3, rb = (g & 7) * 16;
    Ainst[j] = A + (m0 + rb + i2) * K + h * 32 + i3 * 8;
    Alds[j] = &As[h][rb][0];
  }
  // B staging: BN/8 instrs (BIW/wave)
  const short* Binst[BIW];
  short* Blds[BIW];
#pragma unroll
  for (int j = 0; j < BIW; j++) {
    const int g = wave * BIW + j, h = g / BPP, rb = (g % BPP) * 16;
    Binst[j] = Bt + (n0 + rb + i2) * K + h * 32 + i3 * 8;
    Blds[j] = &Bs[h][rb][0];
  }
  const int kbeg = (MODE == 4) ? blockIdx.z * ksl : 0;
  const int kend = kbeg + ((MODE == 4) ? ksl : K);
  for (int k0 = kbeg; k0 < kend; k0 += 64) {
    __syncthreads();
#pragma unroll
    for (int j = 0; j < 4; j++) gload16(Ainst[j] + k0, Alds[j]);
#pragma unroll
    for (int j = 0; j < BIW; j++) gload16(Binst[j] + k0, Blds[j]);
    __syncthreads();
#pragma unroll
    for (int s = 0; s < 2; s++) {
      bf16x8 af[4], bb[NT];
#pragma unroll
      for (int mi = 0; mi < 4; mi++)
        af[mi] = *(const bf16x8*)&As[s][wr + mi * 16 + l15][quad * 8];
#pragma unroll
      for (int ni = 0; ni < NT; ni++)
        bb[ni] = *(const bf16x8*)&Bs[s][wc + ni * 16 + l15][quad * 8];
#pragma unroll
      for (int mi = 0; mi < 4; mi++)
#pragma unroll
        for (int ni = 0; ni < NT; ni++)
          acc[mi][ni] = __builtin_amdgcn_mfma_f32_16x16x32_bf16(af[mi], bb[ni], acc[mi][ni], 0, 0, 0);
    }
  }
  const bool hb = (MODE == 0) && (bias != nullptr);
  const bool ha = (MODE == 0) && (add != nullptr);
  float* dstp = (MODE == 4) ? ((blockIdx.z == 0) ? Cf : Cf2) : Cf;
#pragma unroll
  for (int mi = 0; mi < 4; mi++) {
#pragma unroll
    for (int ni = 0; ni < NT; ni++) {
      long mbase = m0 + wr + mi * 16 + quad * 4;
      long n = n0 + wc + ni * 16 + l15;
#pragma unroll
      for (int r = 0; r < 4; r++) {
        float v = acc[mi][ni][r];
        if (MODE == 0) {
          long idx = (mbase + r) * N + n;
          if (hb) v += bias[n];
          if (ha) v += add[idx];
          Cf[idx] = v;
        } else if (MODE == 3) {
          short* db = Cb;
          long nn = n;
          if (nn >= INTER) { db = Cb2; nn -= INTER; }
          db[(mbase + r) * INTER + nn] = f2bf(v);
        } else {
          dstp[(mbase + r) * N + n] = v;
        }
      }
    }
  }
}

// ---------------- silu combine: g = bf16(silu(g) * u)  (in-place on g) ----------------
__global__ __launch_bounds__(256) void k_silu(const short* __restrict__ u,
                                              short* __restrict__ g) {
  const long n = (long)S_LEN * INTER;
  for (long i = ((long)blockIdx.x * 256 + threadIdx.x) * 8; i < n;
       i += (long)gridDim.x * 256 * 8) {
    bf16x8 gv = *(const bf16x8*)(g + i);
    bf16x8 uv = *(const bf16x8*)(u + i);
    bf16x8 o;
#pragma unroll
    for (int j = 0; j < 8; j++) {
      float gf = bf2f(gv[j]);
      float uf = bf2f(uv[j]);
      float sg = gf / (1.f + __expf(-gf));
      o[j] = f2bf(sg * uf);
    }
    *(bf16x8*)(g + i) = o;
  }
}

// ---------------- final reduce: out = out(partial1) + p0 + h2 ----------------
__global__ __launch_bounds__(256) void k_finish(const float* __restrict__ p0,
                                                const float* __restrict__ h2,
                                                float* __restrict__ out) {
  const long n = (long)S_LEN * HIDN;
  for (long i = ((long)blockIdx.x * 256 + threadIdx.x) * 4; i < n;
       i += (long)gridDim.x * 256 * 4) {
    float4 a = *(const float4*)(out + i);
    float4 b = *(const float4*)(p0 + i);
    float4 c = *(const float4*)(h2 + i);
    a.x += b.x + c.x;
    a.y += b.y + c.y;
    a.z += b.z + c.z;
    a.w += b.w + c.w;
    *(float4*)(out + i) = a;
  }
}

// ---------------- block means of q and k (pre-RoPE) ----------------
__global__ __launch_bounds__(256) void k_blockmean(const float* __restrict__ qkv,
                                                   float* __restrict__ qm,
                                                   float* __restrict__ km) {
  int id = blockIdx.x * 256 + threadIdx.x;  // 32 * 2560
  int qb = id / 2560, c = id % 2560;        // cols 0..2559 = q(2048) + k(512)
  const float* base = qkv + (long)qb * 64 * NQKV + c;
  float acc = 0.f;
  for (int s = 0; s < 64; s++) acc += base[(long)s * NQKV];
  acc *= (1.f / 64.f);
  if (c < 2048) qm[(long)qb * 2048 + c] = acc;
  else km[(long)qb * 512 + (c - 2048)] = acc;
}

// ---------------- gate projections qg = qm@gWq, kg = km@gWk ----------------
__global__ __launch_bounds__(128) void k_gateproj(const float* __restrict__ qm,
                                                  const float* __restrict__ km,
                                                  const float* __restrict__ gWq,
                                                  const float* __restrict__ gWk,
                                                  float* __restrict__ qg,
                                                  float* __restrict__ kg) {
  __shared__ float xm[128];
  const int b = blockIdx.x;
  const float* src; const float* W; float* dst;
  if (b < 512) { src = qm + (long)b * 128; W = gWq; dst = qg + (long)b * 128; }
  else { int r = b - 512; src = km + (long)r * 128; W = gWk; dst = kg + (long)r * 128; }
  xm[threadIdx.x] = src[threadIdx.x];
  __syncthreads();
  float acc = 0.f;
  for (int d = 0; d < 128; d++) acc += xm[d] * W[d * GHW + threadIdx.x];
  dst[threadIdx.x] = acc;
}

// ---------------- gate softmax + keep mask ----------------
__global__ __launch_bounds__(64) void k_gatemask(const float* __restrict__ qg,
                                                 const float* __restrict__ kg,
                                                 unsigned char* __restrict__ mask) {
  const int qb = blockIdx.x, h = blockIdx.y;
  __shared__ float qv[128];
  const int t = threadIdx.x;
  qv[t] = qg[((long)qb * 16 + h) * 128 + t];
  qv[t + 64] = qg[((long)qb * 16 + h) * 128 + t + 64];
  __syncthreads();
  const int kb = t;
  float s = NEGF;
  if (kb < 32 && kb <= qb) {
    const float* kr = kg + ((long)kb * 4 + (h >> 2)) * 128;
    float acc = 0.f;
    for (int d = 0; d < 128; d++) acc += qv[d] * kr[d];
    s = acc * 0.08838834764831845f;  // GH^-0.5
  }
  float m = s;
#pragma unroll
  for (int off = 32; off > 0; off >>= 1) m = fmaxf(m, __shfl_xor(m, off, 64));
  float e = (kb < 32 && kb <= qb) ? __expf(s - m) : 0.f;
  float sum = e;
#pragma unroll
  for (int off = 32; off > 0; off >>= 1) sum += __shfl_xor(sum, off, 64);
  if (kb < 32) {
    float gate = e / sum;
    bool keep = (kb <= qb) && (gate >= THRG || kb == qb);
    mask[((long)h * 32 + qb) * 32 + kb] = keep ? 1 : 0;
  }
}

// ---------------- RoPE + cast q,k -> head-major bf16 ----------------
__global__ __launch_bounds__(256) void k_rope(const float* __restrict__ qkv,
                                              const float* __restrict__ cosb,
                                              const float* __restrict__ sinb,
                                              short* __restrict__ q_bf,
                                              short* __restrict__ k_bf) {
  long id = (long)blockIdx.x * 256 + threadIdx.x;  // S * 20 * 64
  int d = (int)(id & 63);
  long rest = id >> 6;
  int head = (int)(rest % 20);
  int s = (int)(rest / 20);
  const float c = cosb[(long)s * HDIM + d];
  const float sn = sinb[(long)s * HDIM + d];
  if (head < HQ) {
    const float* src = qkv + (long)s * NQKV + head * HDIM;
    float x1 = src[d], x2 = src[d + 64];
    short* dst = q_bf + ((long)head * S_LEN + s) * HDIM;
    dst[d] = f2bf(x1 * c - x2 * sn);
    dst[d + 64] = f2bf(x2 * c + x1 * sn);
  } else {
    int hk = head - HQ;
    const float* src = qkv + (long)s * NQKV + 2048 + hk * HDIM;
    float x1 = src[d], x2 = src[d + 64];
    short* dst = k_bf + ((long)hk * S_LEN + s) * HDIM;
    dst[d] = f2bf(x1 * c - x2 * sn);
    dst[d + 64] = f2bf(x2 * c + x1 * sn);
  }
}

// ---------------- v transpose-cast (tiled, coalesced): v_t[hk][d][s] ----------------
__global__ __launch_bounds__(256) void k_vcast_t(const float* __restrict__ qkv,
                                                 short* __restrict__ v_t) {
  __shared__ float t[32][33];
  const int hk = blockIdx.z;
  const int tx = threadIdx.x, ty = threadIdx.y;  // 32 x 8
  const int d0 = blockIdx.x * 32;                // within HDIM
  const int s0 = blockIdx.y * 32;                // within S
  const float* src = qkv + 2560 + (long)hk * HDIM;
#pragma unroll
  for (int i = 0; i < 4; i++) {
    int s = ty + i * 8;
    t[s][tx] = src[(long)(s0 + s) * NQKV + d0 + tx];
  }
  __syncthreads();
  short* dst = v_t + (long)hk * HDIM * S_LEN;
#pragma unroll
  for (int i = 0; i < 4; i++) {
    int d = ty + i * 8;
    dst[(long)(d0 + d) * S_LEN + s0 + tx] = f2bf(t[tx][d]);
  }
}

// ---------------- flash attention: LDS staging + S^T register softmax ----------------
__global__ __launch_bounds__(256) void k_attn(const short* __restrict__ q_bf,
                                              const short* __restrict__ k_bf,
                                              const short* __restrict__ v_t,
                                              const unsigned char* __restrict__ mask,
                                              short* __restrict__ o_bf) {
  const int qb = blockIdx.x, h = blockIdx.y;
  const int tid = threadIdx.x, wave = tid >> 6, lane = tid & 63;
  const int quad = lane >> 4, l15 = lane & 15;
  __shared__ short Ks[4 * 64 * 32];   // panel kd: [row r][32]
  __shared__ short Vs[2 * 128 * 32];  // panel ksb: [d][32]
  __shared__ short Ps[4][16 * 72];    // per-wave P, padded stride 72 shorts
  short* Pw = Ps[wave];
  const int hk = h >> 2;
  const unsigned char* mptr = mask + ((long)h * 32 + qb) * 32;
  const float SCL = 0.08838834764831845f * 1.4426950408889634f;  // D^-.5 * log2e
  const int qrow_g = qb * 64 + wave * 16 + l15;  // this lane's q-row

  // Q B-frags (n = q-row indexed by l15), resident all kernel
  bf16x8 bq[4];
  {
    const short* qrp = q_bf + ((long)h * S_LEN + qrow_g) * HDIM + quad * 8;
#pragma unroll
    for (int kd = 0; kd < 4; kd++) bq[kd] = *(const bf16x8*)(qrp + kd * 32);
  }

  const short* kh = k_bf + (long)hk * S_LEN * HDIM;
  const short* vh = v_t + (long)hk * HDIM * S_LEN;

  const int i2 = lane >> 2, i3 = lane & 3;
  int koff[4], voff[4];
  const int vp = wave >> 1, vhh = wave & 1;
#pragma unroll
  for (int inst = 0; inst < 4; inst++) {
    koff[inst] = (inst * 16 + i2) * HDIM + wave * 32 + i3 * 8;
    voff[inst] = (vhh * 64 + inst * 16 + i2) * S_LEN + vp * 32 + i3 * 8;
  }

  f32x4 accO[8] = {};
  float mrow = -3.0e38f, lrow = 0.f;

  for (int kb = 0; kb <= qb; kb++) {
    if (!mptr[kb]) continue;  // block-uniform
    __syncthreads();  // prior iter's LDS reads done before overwrite
    {
      const int kg = kb * 64 * HDIM;
      const int vg = kb * 64;
#pragma unroll
      for (int inst = 0; inst < 4; inst++) {
        gload16(kh + kg + koff[inst], &Ks[wave * 2048 + inst * 512]);
        gload16(vh + vg + voff[inst], &Vs[vp * 4096 + (vhh * 64 + inst * 16) * 32]);
      }
    }
    __syncthreads();  // all staging landed (compiler drains vmcnt)

    // ---- S^T: 4 subtiles; lane ends with 16 scores for its q-row ----
    f32x4 sv[4];
#pragma unroll
    for (int nt = 0; nt < 4; nt++) {
      f32x4 t = {};
#pragma unroll
      for (int kd = 0; kd < 4; kd++) {
        bf16x8 ka = *(const bf16x8*)&Ks[kd * 2048 + (nt * 16 + l15) * 32 + quad * 8];
        t = __builtin_amdgcn_mfma_f32_16x16x32_bf16(ka, bq[kd], t, 0, 0, 0);
      }
      sv[nt] = t;
    }
    // ---- scale + mask + row max ----
    float lmx = -__builtin_inff();
    if (kb < qb) {
#pragma unroll
      for (int nt = 0; nt < 4; nt++)
#pragma unroll
        for (int r = 0; r < 4; r++) {
          sv[nt][r] *= SCL;
          lmx = fmaxf(lmx, sv[nt][r]);
        }
    } else {  // diagonal block
#pragma unroll
      for (int nt = 0; nt < 4; nt++)
#pragma unroll
        for (int r = 0; r < 4; r++) {
          const int kcol = kb * 64 + nt * 16 + quad * 4 + r;
          sv[nt][r] = (kcol <= qrow_g) ? sv[nt][r] * SCL : -__builtin_inff();
          lmx = fmaxf(lmx, sv[nt][r]);
        }
    }
    lmx = fmaxf(lmx, __shfl_xor(lmx, 16, 64));
    lmx = fmaxf(lmx, __shfl_xor(lmx, 32, 64));
    const float mnew = fmaxf(mrow, lmx);
    const float alpha = __builtin_amdgcn_exp2f(mrow - mnew);
    mrow = mnew;
    // ---- exp2 + sum + packed P write (padded stride, b64) ----
    float psum = 0.f;
#pragma unroll
    for (int nt = 0; nt < 4; nt++) {
#pragma unroll
      for (int r = 0; r < 4; r++) {
        float p = __builtin_amdgcn_exp2f(sv[nt][r] - mnew);
        sv[nt][r] = p;
        psum += p;
      }
      uint2 u;
      u.x = pack_bf2(sv[nt][1], sv[nt][0]);
      u.y = pack_bf2(sv[nt][3], sv[nt][2]);
      *(uint2*)&Pw[l15 * 72 + nt * 16 + quad * 4] = u;
    }
    psum += __shfl_xor(psum, 16, 64);
    psum += __shfl_xor(psum, 32, 64);
    lrow = lrow * alpha + psum;
    // ---- rescale accO (alpha broadcast: lane j<16 holds row j's alpha) ----
    float al[4];
#pragma unroll
    for (int r = 0; r < 4; r++) al[r] = __shfl(alpha, quad * 4 + r, 64);
#pragma unroll
    for (int dt = 0; dt < 8; dt++)
#pragma unroll
      for (int r = 0; r < 4; r++) accO[dt][r] *= al[r];
    // drain this wave's P writes before fragment reads (per-wave buffer)
    asm volatile("s_waitcnt lgkmcnt(0)" ::: "memory");
    // ---- PV: P(16x64) @ V^T panels ----
    bf16x8 pf[2];
#pragma unroll
    for (int ksb = 0; ksb < 2; ksb++)
      pf[ksb] = *(const bf16x8*)&Pw[l15 * 72 + ksb * 32 + quad * 8];
#pragma unroll
    for (int dt = 0; dt < 8; dt++) {
#pragma unroll
      for (int ksb = 0; ksb < 2; ksb++) {
        bf16x8 vf = *(const bf16x8*)&Vs[ksb * 4096 + (dt * 16 + l15) * 32 + quad * 8];
        accO[dt] = __builtin_amdgcn_mfma_f32_16x16x32_bf16(pf[ksb], vf, accO[dt], 0, 0, 0);
      }
    }
  }
  // ---- epilogue: normalize by l (broadcast like alpha) and store ----
  const float linv = 1.f / lrow;
  float li[4];
#pragma unroll
  for (int r = 0; r < 4; r++) li[r] = __shfl(linv, quad * 4 + r, 64);
#pragma unroll
  for (int r = 0; r < 4; r++) {
    const long srow = (long)qb * 64 + wave * 16 + quad * 4 + r;
#pragma unroll
    for (int dt = 0; dt < 8; dt++)
      o_bf[srow * HIDN + h * HDIM + dt * 16 + l15] = f2bf(accO[dt][r] * li[r]);
  }
}

// ---------------- workspace layout ----------------
static constexpr size_t SZ_WQKVT = (size_t)NQKV * HIDN * 2;
static constexpr size_t SZ_WOT = (size_t)HIDN * HIDN * 2;
static constexpr size_t SZ_WBIG = (size_t)INTER * HIDN * 2;
static constexpr size_t OFF_WQKVT = 0;
static constexpr size_t OFF_WOT = OFF_WQKVT + SZ_WQKVT;
static constexpr size_t OFF_WGATET = OFF_WOT + SZ_WOT;
static constexpr size_t OFF_WUPT = OFF_WGATET + SZ_WBIG;   // MUST stay adjacent to WGATET (merged gate/up GEMM)
static constexpr size_t OFF_WDOWNT = OFF_WUPT + SZ_WBIG;
static constexpr size_t OFF_BIAS = OFF_WDOWNT + SZ_WBIG;
static constexpr size_t OFF_MASK = OFF_BIAS + 3072 * 4 + 4096;
static constexpr size_t OFF_QM = OFF_MASK + 16 * 32 * 32 + 4096;
static constexpr size_t OFF_KM = OFF_QM + (size_t)32 * 16 * 128 * 4;
static constexpr size_t OFF_QG = OFF_KM + (size_t)32 * 4 * 128 * 4;
static constexpr size_t OFF_KG = OFF_QG + (size_t)32 * 16 * 128 * 4;
static constexpr size_t OFF_H2 = OFF_KG + (size_t)32 * 4 * 128 * 4;
static constexpr size_t OFF_H3 = OFF_H2 + (size_t)S_LEN * HIDN * 4;
static constexpr size_t OFF_REGA = OFF_H3 + (size_t)S_LEN * HIDN * 2;
//   REGA timeline: h_bf | q_bf | k_bf | v_t | o_bf  ->  u_bf (23.1MB, after Wo)
//                  ->  p0 for Wdown split-K (16.8MB, after silu)
static constexpr size_t RA_HBF = 0;
static constexpr size_t RA_QBF = RA_HBF + (size_t)S_LEN * HIDN * 2;
static constexpr size_t RA_KBF = RA_QBF + (size_t)HQ * S_LEN * HDIM * 2;
static constexpr size_t RA_VT = RA_KBF + (size_t)HKV * S_LEN * HDIM * 2;
static constexpr size_t RA_OBF = RA_VT + (size_t)HKV * HDIM * S_LEN * 2;
static constexpr size_t SZ_REGA = RA_OBF + (size_t)S_LEN * HIDN * 2;
static constexpr size_t OFF_REGB = OFF_REGA + SZ_REGA;
//   REGB timeline: qkv_f32 (25.2MB) -> Wo split-K p0 (16.8MB)
//                  -> g_bf / act_bf (23.1MB, silu in-place). All sequential.
static constexpr size_t SZ_REGB = (size_t)S_LEN * NQKV * 4;
static constexpr size_t TOTAL_WS = OFF_REGB + SZ_REGB;

extern "C" void kernel_launch(void* const* d_in, const int* in_sizes, int n_in,
                              void* d_out, int out_size, void* d_ws, size_t ws_size,
                              hipStream_t stream) {
  const float* hidden = (const float*)d_in[0];
  const float* cosb = (const float*)d_in[1];
  const float* sinb = (const float*)d_in[2];
  const float* ln1 = (const float*)d_in[3];
  const float* ln2 = (const float*)d_in[4];
  const float* Wq = (const float*)d_in[5];
  const float* bq = (const float*)d_in[6];
  const float* Wk = (const float*)d_in[7];
  const float* bk = (const float*)d_in[8];
  const float* Wv = (const float*)d_in[9];
  const float* bv = (const float*)d_in[10];
  const float* Wo = (const float*)d_in[11];
  const float* gWq = (const float*)d_in[12];
  const float* gWk = (const float*)d_in[13];
  const float* Wgate = (const float*)d_in[14];
  const float* Wup = (const float*)d_in[15];
  const float* Wdown = (const float*)d_in[16];

  if (ws_size < TOTAL_WS) return;  // workspace too small; fail visibly

  char* ws = (char*)d_ws;
  short* WqkvT = (short*)(ws + OFF_WQKVT);
  short* WoT = (short*)(ws + OFF_WOT);
  short* WgateT = (short*)(ws + OFF_WGATET);
  short* WupT = (short*)(ws + OFF_WUPT);
  short* WdownT = (short*)(ws + OFF_WDOWNT);
  float* biasqkv = (float*)(ws + OFF_BIAS);
  unsigned char* maskb = (unsigned char*)(ws + OFF_MASK);
  float* qm = (float*)(ws + OFF_QM);
  float* km = (float*)(ws + OFF_KM);
  float* qg = (float*)(ws + OFF_QG);
  float* kg = (float*)(ws + OFF_KG);
  float* h2 = (float*)(ws + OFF_H2);
  short* h3_bf = (short*)(ws + OFF_H3);
  short* h_bf = (short*)(ws + OFF_REGA + RA_HBF);
  short* q_bf = (short*)(ws + OFF_REGA + RA_QBF);
  short* k_bf = (short*)(ws + OFF_REGA + RA_KBF);
  short* v_t = (short*)(ws + OFF_REGA + RA_VT);
  short* o_bf = (short*)(ws + OFF_REGA + RA_OBF);
  short* u_bf = (short*)(ws + OFF_REGA);      // gate/up 'up' output (REGA dead by then)
  float* p0b = (float*)(ws + OFF_REGA);       // Wdown split-K p0 (u_bf dead by then)
  float* qkv_f = (float*)(ws + OFF_REGB);
  float* p0a = (float*)(ws + OFF_REGB);       // Wo split-K p0 (qkv_f dead by then)
  short* g_bf = (short*)(ws + OFF_REGB);      // gate output / act after silu (p0a dead)
  float* outp = (float*)d_out;

  dim3 tb(32, 8);
  // weight transposes (fp32 -> bf16, N x K)
  k_transpose_cast<<<dim3(64, 64), tb, 0, stream>>>(Wq, WqkvT, HIDN, 2048);
  k_transpose_cast<<<dim3(16, 64), tb, 0, stream>>>(Wk, WqkvT + (size_t)2048 * HIDN, HIDN, 512);
  k_transpose_cast<<<dim3(16, 64), tb, 0, stream>>>(Wv, WqkvT + (size_t)2560 * HIDN, HIDN, 512);
  k_transpose_cast<<<dim3(64, 64), tb, 0, stream>>>(Wo, WoT, HIDN, HIDN);
  k_transpose_cast<<<dim3(176, 64), tb, 0, stream>>>(Wgate, WgateT, HIDN, INTER);
  k_transpose_cast<<<dim3(176, 64), tb, 0, stream>>>(Wup, WupT, HIDN, INTER);
  k_transpose_cast<<<dim3(64, 176), tb, 0, stream>>>(Wdown, WdownT, INTER, HIDN);
  k_bias_concat<<<12, 256, 0, stream>>>(bq, bk, bv, biasqkv);

  // h = RMS(hidden, ln1) -> bf16
  k_rms<<<S_LEN, 256, 0, stream>>>(hidden, ln1, h_bf);
  // qkv = h @ [Wq|Wk|Wv] + bias  (fp32)  [BN=64: 768 blocks, 3/CU]
  k_gemm<0, 64><<<dim3(NQKV / 64, S_LEN / 128), 256, 0, stream>>>(
      h_bf, WqkvT, qkv_f, nullptr, nullptr, nullptr, biasqkv, nullptr, S_LEN, NQKV, HIDN, HIDN);
  // gate path (pre-RoPE q,k)
  k_blockmean<<<320, 256, 0, stream>>>(qkv_f, qm, km);
  k_gateproj<<<640, 128, 0, stream>>>(qm, km, gWq, gWk, qg, kg);
  k_gatemask<<<dim3(32, 16), 64, 0, stream>>>(qg, kg, maskb);
  // RoPE + layout change
  k_rope<<<10240, 256, 0, stream>>>(qkv_f, cosb, sinb, q_bf, k_bf);
  k_vcast_t<<<dim3(4, 64, 4), tb, 0, stream>>>(qkv_f, v_t);
  // attention
  k_attn<<<dim3(32, 16), 256, 0, stream>>>(q_bf, k_bf, v_t, maskb, o_bf);
  // Wo partials = o @ Wo  (split-K x2: 1024 blocks, 4/CU; reduce fused into rms)
  k_gemm<4, 64><<<dim3(HIDN / 64, S_LEN / 128, 2), 256, 0, stream>>>(
      o_bf, WoT, p0a, h2, nullptr, nullptr, nullptr, nullptr, S_LEN, HIDN, HIDN, HIDN / 2);
  // h2 = p0 + p1 + hidden ; h3 = RMS(h2, ln2) -> bf16
  k_rms_fin<<<S_LEN, 256, 0, stream>>>(p0a, hidden, ln2, h2, h3_bf);
  // merged gate+up: [g|u] = h3 @ [Wgate|Wup]  (N=11264, 1408 blocks, 5.5/CU)
  k_gemm<3, 128><<<dim3(2 * INTER / 128, S_LEN / 128), 256, 0, stream>>>(
      h3_bf, WgateT, nullptr, nullptr, g_bf, u_bf, nullptr, nullptr, S_LEN, 2 * INTER, HIDN, HIDN);
  // act = silu(g) * u  (in-place into g_bf)
  k_silu<<<2048, 256, 0, stream>>>(u_bf, g_bf);
  // out partials = act @ Wdown  (split-K x2: 1024 blocks, 4/CU)
  k_gemm<4, 64><<<dim3(HIDN / 64, S_LEN / 128, 2), 256, 0, stream>>>(
      g_bf, WdownT, p0b, outp, nullptr, nullptr, nullptr, nullptr, S_LEN, HIDN, INTER, INTER / 2);
  // out = out + p0 + h2
  k_finish<<<2048, 256, 0, stream>>>(p0b, h2, outp);
  (void)in_sizes; (void)n_in; (void)out_size;
}

// Round 6
// 620.619 us; speedup vs baseline: 1.1806x; 1.0259x over previous
//
#include <hip/hip_runtime.h>
#include <stdint.h>
#include <stddef.h>

// ---------------- problem constants ----------------
#define S_LEN 2048
#define HIDN  2048
#define HQ    16
#define HKV   4
#define HDIM  128
#define NQKV  3072      // HQ*D + 2*HKV*D
#define QBLK  32        // S/64
#define GHW   128
#define INTER 5632
#define NEGF  (-1e30f)
#define THRG  0.004f

typedef short bf16x8 __attribute__((ext_vector_type(8)));
typedef float f32x4  __attribute__((ext_vector_type(4)));

__device__ __forceinline__ short f2bf(float f) {
  union { float f; unsigned u; } v; v.f = f;
  unsigned r = (v.u + 0x7FFFu + ((v.u >> 16) & 1u)) >> 16;
  return (short)r;
}
__device__ __forceinline__ float bf2f(short s) {
  union { float f; unsigned u; } v; v.u = ((unsigned)(unsigned short)s) << 16;
  return v.f;
}
__device__ __forceinline__ void gload16(const void* g, void* l) {
  __builtin_amdgcn_global_load_lds(
      (const __attribute__((address_space(1))) void*)g,
      (__attribute__((address_space(3))) void*)l, 16, 0, 0);
}
// pack two f32 -> [bf16(hi)<<16 | bf16(lo)] via byte-select (truncation)
__device__ __forceinline__ unsigned pack_bf2(float hi, float lo) {
  return __builtin_amdgcn_perm(__float_as_uint(hi), __float_as_uint(lo), 0x07060302u);
}

// ---------------- transpose + cast fp32 (R x C) -> bf16 (C x R) ----------------
__global__ __launch_bounds__(256) void k_transpose_cast(
    const float* __restrict__ src, short* __restrict__ dst, int R, int C) {
  __shared__ float t[32][33];
  const int tx = threadIdx.x, ty = threadIdx.y;
  const int x = blockIdx.x * 32 + tx;
  const int y0 = blockIdx.y * 32;
#pragma unroll
  for (int i = 0; i < 4; i++) {
    int yy = ty + i * 8;
    t[yy][tx] = src[(long)(y0 + yy) * C + x];
  }
  __syncthreads();
  const int xo = blockIdx.y * 32 + tx;
  const int yo0 = blockIdx.x * 32;
#pragma unroll
  for (int i = 0; i < 4; i++) {
    int yy = ty + i * 8;
    dst[(long)(yo0 + yy) * R + xo] = f2bf(t[tx][yy]);
  }
}

// ---------------- transpose + cast + 16-row interleave (gate/up merge) ----------------
// dst row for source col j: (j>>4)*32 + phase*16 + (j&15)
// phase 0 = gate, phase 1 = up. Produces Wgu^T[2*INTER][K] where 32-row group g
// = {gate cols 16g..16g+15, up cols 16g..16g+15}.
__global__ __launch_bounds__(256) void k_transpose_cast_ilv(
    const float* __restrict__ src, short* __restrict__ dst, int R, int C, int phase) {
  __shared__ float t[32][33];
  const int tx = threadIdx.x, ty = threadIdx.y;
  const int x = blockIdx.x * 32 + tx;
  const int y0 = blockIdx.y * 32;
#pragma unroll
  for (int i = 0; i < 4; i++) {
    int yy = ty + i * 8;
    t[yy][tx] = src[(long)(y0 + yy) * C + x];
  }
  __syncthreads();
  const int xo = blockIdx.y * 32 + tx;
  const int yo0 = blockIdx.x * 32;
#pragma unroll
  for (int i = 0; i < 4; i++) {
    int j = yo0 + ty + i * 8;                       // source col
    long orow = (long)(j >> 4) * 32 + phase * 16 + (j & 15);
    dst[orow * R + xo] = f2bf(t[tx][ty + i * 8]);
  }
}

// ---------------- concat qkv bias ----------------
__global__ void k_bias_concat(const float* __restrict__ bq, const float* __restrict__ bk,
                              const float* __restrict__ bv, float* __restrict__ out) {
  int i = blockIdx.x * 256 + threadIdx.x;
  if (i < 2048) out[i] = bq[i];
  else if (i < 2560) out[i] = bk[i - 2048];
  else out[i] = bv[i - 2560];
}

// ---------------- RMSNorm fp32 -> bf16 ----------------
__global__ __launch_bounds__(256) void k_rms(const float* __restrict__ x,
                                             const float* __restrict__ w,
                                             short* __restrict__ out) {
  const int row = blockIdx.x;
  const float* xr = x + (long)row * HIDN;
  float v[8];
  float ss = 0.f;
#pragma unroll
  for (int i = 0; i < 8; i++) {
    v[i] = xr[threadIdx.x + i * 256];
    ss += v[i] * v[i];
  }
#pragma unroll
  for (int off = 32; off > 0; off >>= 1) ss += __shfl_down(ss, off, 64);
  __shared__ float red[4];
  const int wave = threadIdx.x >> 6, lane = threadIdx.x & 63;
  if (lane == 0) red[wave] = ss;
  __syncthreads();
  float tot = red[0] + red[1] + red[2] + red[3];
  float rs = rsqrtf(tot / (float)HIDN + 1e-6f);
#pragma unroll
  for (int i = 0; i < 8; i++) {
    int c = threadIdx.x + i * 256;
    out[(long)row * HIDN + c] = f2bf(v[i] * rs * w[c]);
  }
}

// ---------------- fused split-K reduce + RMSNorm ----------------
// h2 = p0 + h2(partial1) + hid ; out = bf16(rms(h2) * w)
__global__ __launch_bounds__(256) void k_rms_fin(const float* __restrict__ p0,
                                                 const float* __restrict__ hid,
                                                 const float* __restrict__ w,
                                                 float* __restrict__ h2,
                                                 short* __restrict__ out) {
  const int row = blockIdx.x;
  const long base = (long)row * HIDN;
  float v[8];
  float ss = 0.f;
#pragma unroll
  for (int i = 0; i < 8; i++) {
    int c = threadIdx.x + i * 256;
    float t = p0[base + c] + h2[base + c] + hid[base + c];
    h2[base + c] = t;
    v[i] = t;
    ss += t * t;
  }
#pragma unroll
  for (int off = 32; off > 0; off >>= 1) ss += __shfl_down(ss, off, 64);
  __shared__ float red[4];
  const int wave = threadIdx.x >> 6, lane = threadIdx.x & 63;
  if (lane == 0) red[wave] = ss;
  __syncthreads();
  float tot = red[0] + red[1] + red[2] + red[3];
  float rs = rsqrtf(tot / (float)HIDN + 1e-6f);
#pragma unroll
  for (int i = 0; i < 8; i++) {
    int c = threadIdx.x + i * 256;
    out[base + c] = f2bf(v[i] * rs * w[c]);
  }
}

// ---------------- GEMM: C[M,N] = A[M,K](bf16) * Bt[N,K](bf16)^T  ----------------
// MODE 0: Cf = acc + bias? + add?   (fp32 out)
// MODE 4: split-K partial: z==0 -> Cf, z==1 -> Cf2 (no bias/add)
// MODE 5: gate/up interleaved (Bt = Wgu^T, 16-row groups alternate gate/up):
//         Cb[row*INTER + col] = bf16(silu(acc_gate) * acc_up), col count = N/2
// BK=64: tiles stored as two k-half panels [2][rows][32].
// ksl = K-slice length per z (== K when gridDim.z == 1).
template <int MODE, int BN>
__global__ __launch_bounds__(256) void k_gemm(
    const short* __restrict__ A, const short* __restrict__ Bt,
    float* __restrict__ Cf, float* __restrict__ Cf2,
    short* __restrict__ Cb,
    const float* __restrict__ bias, const float* __restrict__ add,
    int M, int N, int K, int ksl) {
  constexpr int NT = BN / 32;   // n-tiles per wave
  constexpr int BIW = BN / 32;  // per-wave B staging instrs
  constexpr int BPP = BN / 16;  // B staging instrs per k-half panel
  __shared__ short As[2][128][32];
  __shared__ short Bs[2][BN][32];
  const int tid = threadIdx.x;
  const int wave = tid >> 6, lane = tid & 63, quad = lane >> 4, l15 = lane & 15;
  const long m0 = (long)blockIdx.y * 128, n0 = (long)blockIdx.x * BN;
  const int wr = (wave >> 1) * 64, wc = (wave & 1) * (BN / 2);
  const int i2 = lane >> 2, i3 = lane & 3;
  f32x4 acc[4][NT] = {};
  // A staging: 16 instrs (4/wave). instr g: k-half h=g>>3, rows (g&7)*16..+15
  const short* Ainst[4];
  short* Alds[4];
#pragma unroll
  for (int j = 0; j < 4; j++) {
    const int g = wave * 4 + j, h = g >> 3, rb = (g & 7) * 16;
    Ainst[j] = A + (m0 + rb + i2) * K + h * 32 + i3 * 8;
    Alds[j] = &As[h][rb][0];
  }
  // B staging: BN/8 instrs (BIW/wave)
  const short* Binst[BIW];
  short* Blds[BIW];
#pragma unroll
  for (int j = 0; j < BIW; j++) {
    const int g = wave * BIW + j, h = g / BPP, rb = (g % BPP) * 16;
    Binst[j] = Bt + (n0 + rb + i2) * K + h * 32 + i3 * 8;
    Blds[j] = &Bs[h][rb][0];
  }
  const int kbeg = (MODE == 4) ? blockIdx.z * ksl : 0;
  const int kend = kbeg + ((MODE == 4) ? ksl : K);
  for (int k0 = kbeg; k0 < kend; k0 += 64) {
    __syncthreads();
#pragma unroll
    for (int j = 0; j < 4; j++) gload16(Ainst[j] + k0, Alds[j]);
#pragma unroll
    for (int j = 0; j < BIW; j++) gload16(Binst[j] + k0, Blds[j]);
    __syncthreads();
#pragma unroll
    for (int s = 0; s < 2; s++) {
      bf16x8 af[4], bb[NT];
#pragma unroll
      for (int mi = 0; mi < 4; mi++)
        af[mi] = *(const bf16x8*)&As[s][wr + mi * 16 + l15][quad * 8];
#pragma unroll
      for (int ni = 0; ni < NT; ni++)
        bb[ni] = *(const bf16x8*)&Bs[s][wc + ni * 16 + l15][quad * 8];
#pragma unroll
      for (int mi = 0; mi < 4; mi++)
#pragma unroll
        for (int ni = 0; ni < NT; ni++)
          acc[mi][ni] = __builtin_amdgcn_mfma_f32_16x16x32_bf16(af[mi], bb[ni], acc[mi][ni], 0, 0, 0);
    }
  }
  const bool hb = (MODE == 0) && (bias != nullptr);
  const bool ha = (MODE == 0) && (add != nullptr);
  float* dstp = (MODE == 4) ? ((blockIdx.z == 0) ? Cf : Cf2) : Cf;
#pragma unroll
  for (int mi = 0; mi < 4; mi++) {
    if (MODE == 5) {
      // ni even = gate, ni+1 = up, SAME 16 columns. col base = (n0+wc)/2.
#pragma unroll
      for (int ni2 = 0; ni2 < NT / 2; ni2++) {
        long mbase = m0 + wr + mi * 16 + quad * 4;
        long col = (n0 + wc) / 2 + ni2 * 16 + l15;
#pragma unroll
        for (int r = 0; r < 4; r++) {
          float g = acc[mi][2 * ni2][r];
          float u = acc[mi][2 * ni2 + 1][r];
          float sg = g / (1.f + __expf(-g));
          Cb[(mbase + r) * INTER + col] = f2bf(sg * u);
        }
      }
    } else {
#pragma unroll
      for (int ni = 0; ni < NT; ni++) {
        long mbase = m0 + wr + mi * 16 + quad * 4;
        long n = n0 + wc + ni * 16 + l15;
#pragma unroll
        for (int r = 0; r < 4; r++) {
          float v = acc[mi][ni][r];
          if (MODE == 0) {
            long idx = (mbase + r) * N + n;
            if (hb) v += bias[n];
            if (ha) v += add[idx];
            Cf[idx] = v;
          } else {
            dstp[(mbase + r) * N + n] = v;
          }
        }
      }
    }
  }
}

// ---------------- final reduce: out = out(partial1) + p0 + h2 ----------------
__global__ __launch_bounds__(256) void k_finish(const float* __restrict__ p0,
                                                const float* __restrict__ h2,
                                                float* __restrict__ out) {
  const long n = (long)S_LEN * HIDN;
  for (long i = ((long)blockIdx.x * 256 + threadIdx.x) * 4; i < n;
       i += (long)gridDim.x * 256 * 4) {
    float4 a = *(const float4*)(out + i);
    float4 b = *(const float4*)(p0 + i);
    float4 c = *(const float4*)(h2 + i);
    a.x += b.x + c.x;
    a.y += b.y + c.y;
    a.z += b.z + c.z;
    a.w += b.w + c.w;
    *(float4*)(out + i) = a;
  }
}

// ---------------- block means of q and k (pre-RoPE) ----------------
__global__ __launch_bounds__(256) void k_blockmean(const float* __restrict__ qkv,
                                                   float* __restrict__ qm,
                                                   float* __restrict__ km) {
  int id = blockIdx.x * 256 + threadIdx.x;  // 32 * 2560
  int qb = id / 2560, c = id % 2560;        // cols 0..2559 = q(2048) + k(512)
  const float* base = qkv + (long)qb * 64 * NQKV + c;
  float acc = 0.f;
  for (int s = 0; s < 64; s++) acc += base[(long)s * NQKV];
  acc *= (1.f / 64.f);
  if (c < 2048) qm[(long)qb * 2048 + c] = acc;
  else km[(long)qb * 512 + (c - 2048)] = acc;
}

// ---------------- gate projections qg = qm@gWq, kg = km@gWk ----------------
__global__ __launch_bounds__(128) void k_gateproj(const float* __restrict__ qm,
                                                  const float* __restrict__ km,
                                                  const float* __restrict__ gWq,
                                                  const float* __restrict__ gWk,
                                                  float* __restrict__ qg,
                                                  float* __restrict__ kg) {
  __shared__ float xm[128];
  const int b = blockIdx.x;
  const float* src; const float* W; float* dst;
  if (b < 512) { src = qm + (long)b * 128; W = gWq; dst = qg + (long)b * 128; }
  else { int r = b - 512; src = km + (long)r * 128; W = gWk; dst = kg + (long)r * 128; }
  xm[threadIdx.x] = src[threadIdx.x];
  __syncthreads();
  float acc = 0.f;
  for (int d = 0; d < 128; d++) acc += xm[d] * W[d * GHW + threadIdx.x];
  dst[threadIdx.x] = acc;
}

// ---------------- gate softmax + keep mask ----------------
__global__ __launch_bounds__(64) void k_gatemask(const float* __restrict__ qg,
                                                 const float* __restrict__ kg,
                                                 unsigned char* __restrict__ mask) {
  const int qb = blockIdx.x, h = blockIdx.y;
  __shared__ float qv[128];
  const int t = threadIdx.x;
  qv[t] = qg[((long)qb * 16 + h) * 128 + t];
  qv[t + 64] = qg[((long)qb * 16 + h) * 128 + t + 64];
  __syncthreads();
  const int kb = t;
  float s = NEGF;
  if (kb < 32 && kb <= qb) {
    const float* kr = kg + ((long)kb * 4 + (h >> 2)) * 128;
    float acc = 0.f;
    for (int d = 0; d < 128; d++) acc += qv[d] * kr[d];
    s = acc * 0.08838834764831845f;  // GH^-0.5
  }
  float m = s;
#pragma unroll
  for (int off = 32; off > 0; off >>= 1) m = fmaxf(m, __shfl_xor(m, off, 64));
  float e = (kb < 32 && kb <= qb) ? __expf(s - m) : 0.f;
  float sum = e;
#pragma unroll
  for (int off = 32; off > 0; off >>= 1) sum += __shfl_xor(sum, off, 64);
  if (kb < 32) {
    float gate = e / sum;
    bool keep = (kb <= qb) && (gate >= THRG || kb == qb);
    mask[((long)h * 32 + qb) * 32 + kb] = keep ? 1 : 0;
  }
}

// ---------------- RoPE + cast q,k -> head-major bf16 ----------------
__global__ __launch_bounds__(256) void k_rope(const float* __restrict__ qkv,
                                              const float* __restrict__ cosb,
                                              const float* __restrict__ sinb,
                                              short* __restrict__ q_bf,
                                              short* __restrict__ k_bf) {
  long id = (long)blockIdx.x * 256 + threadIdx.x;  // S * 20 * 64
  int d = (int)(id & 63);
  long rest = id >> 6;
  int head = (int)(rest % 20);
  int s = (int)(rest / 20);
  const float c = cosb[(long)s * HDIM + d];
  const float sn = sinb[(long)s * HDIM + d];
  if (head < HQ) {
    const float* src = qkv + (long)s * NQKV + head * HDIM;
    float x1 = src[d], x2 = src[d + 64];
    short* dst = q_bf + ((long)head * S_LEN + s) * HDIM;
    dst[d] = f2bf(x1 * c - x2 * sn);
    dst[d + 64] = f2bf(x2 * c + x1 * sn);
  } else {
    int hk = head - HQ;
    const float* src = qkv + (long)s * NQKV + 2048 + hk * HDIM;
    float x1 = src[d], x2 = src[d + 64];
    short* dst = k_bf + ((long)hk * S_LEN + s) * HDIM;
    dst[d] = f2bf(x1 * c - x2 * sn);
    dst[d + 64] = f2bf(x2 * c + x1 * sn);
  }
}

// ---------------- v transpose-cast (tiled, coalesced): v_t[hk][d][s] ----------------
__global__ __launch_bounds__(256) void k_vcast_t(const float* __restrict__ qkv,
                                                 short* __restrict__ v_t) {
  __shared__ float t[32][33];
  const int hk = blockIdx.z;
  const int tx = threadIdx.x, ty = threadIdx.y;  // 32 x 8
  const int d0 = blockIdx.x * 32;                // within HDIM
  const int s0 = blockIdx.y * 32;                // within S
  const float* src = qkv + 2560 + (long)hk * HDIM;
#pragma unroll
  for (int i = 0; i < 4; i++) {
    int s = ty + i * 8;
    t[s][tx] = src[(long)(s0 + s) * NQKV + d0 + tx];
  }
  __syncthreads();
  short* dst = v_t + (long)hk * HDIM * S_LEN;
#pragma unroll
  for (int i = 0; i < 4; i++) {
    int d = ty + i * 8;
    dst[(long)(d0 + d) * S_LEN + s0 + tx] = f2bf(t[tx][d]);
  }
}

// ---------------- flash attention: LDS staging + S^T register softmax ----------------
__global__ __launch_bounds__(256) void k_attn(const short* __restrict__ q_bf,
                                              const short* __restrict__ k_bf,
                                              const short* __restrict__ v_t,
                                              const unsigned char* __restrict__ mask,
                                              short* __restrict__ o_bf) {
  const int qb = blockIdx.x, h = blockIdx.y;
  const int tid = threadIdx.x, wave = tid >> 6, lane = tid & 63;
  const int quad = lane >> 4, l15 = lane & 15;
  __shared__ short Ks[4 * 64 * 32];   // panel kd: [row r][32]
  __shared__ short Vs[2 * 128 * 32];  // panel ksb: [d][32]
  __shared__ short Ps[4][16 * 72];    // per-wave P, padded stride 72 shorts
  short* Pw = Ps[wave];
  const int hk = h >> 2;
  const unsigned char* mptr = mask + ((long)h * 32 + qb) * 32;
  const float SCL = 0.08838834764831845f * 1.4426950408889634f;  // D^-.5 * log2e
  const int qrow_g = qb * 64 + wave * 16 + l15;  // this lane's q-row

  // Q B-frags (n = q-row indexed by l15), resident all kernel
  bf16x8 bq[4];
  {
    const short* qrp = q_bf + ((long)h * S_LEN + qrow_g) * HDIM + quad * 8;
#pragma unroll
    for (int kd = 0; kd < 4; kd++) bq[kd] = *(const bf16x8*)(qrp + kd * 32);
  }

  const short* kh = k_bf + (long)hk * S_LEN * HDIM;
  const short* vh = v_t + (long)hk * HDIM * S_LEN;

  const int i2 = lane >> 2, i3 = lane & 3;
  int koff[4], voff[4];
  const int vp = wave >> 1, vhh = wave & 1;
#pragma unroll
  for (int inst = 0; inst < 4; inst++) {
    koff[inst] = (inst * 16 + i2) * HDIM + wave * 32 + i3 * 8;
    voff[inst] = (vhh * 64 + inst * 16 + i2) * S_LEN + vp * 32 + i3 * 8;
  }

  f32x4 accO[8] = {};
  float mrow = -3.0e38f, lrow = 0.f;

  for (int kb = 0; kb <= qb; kb++) {
    if (!mptr[kb]) continue;  // block-uniform
    __syncthreads();  // prior iter's LDS reads done before overwrite
    {
      const int kg = kb * 64 * HDIM;
      const int vg = kb * 64;
#pragma unroll
      for (int inst = 0; inst < 4; inst++) {
        gload16(kh + kg + koff[inst], &Ks[wave * 2048 + inst * 512]);
        gload16(vh + vg + voff[inst], &Vs[vp * 4096 + (vhh * 64 + inst * 16) * 32]);
      }
    }
    __syncthreads();  // all staging landed (compiler drains vmcnt)

    // ---- S^T: 4 subtiles; lane ends with 16 scores for its q-row ----
    f32x4 sv[4];
#pragma unroll
    for (int nt = 0; nt < 4; nt++) {
      f32x4 t = {};
#pragma unroll
      for (int kd = 0; kd < 4; kd++) {
        bf16x8 ka = *(const bf16x8*)&Ks[kd * 2048 + (nt * 16 + l15) * 32 + quad * 8];
        t = __builtin_amdgcn_mfma_f32_16x16x32_bf16(ka, bq[kd], t, 0, 0, 0);
      }
      sv[nt] = t;
    }
    // ---- scale + mask + row max ----
    float lmx = -__builtin_inff();
    if (kb < qb) {
#pragma unroll
      for (int nt = 0; nt < 4; nt++)
#pragma unroll
        for (int r = 0; r < 4; r++) {
          sv[nt][r] *= SCL;
          lmx = fmaxf(lmx, sv[nt][r]);
        }
    } else {  // diagonal block
#pragma unroll
      for (int nt = 0; nt < 4; nt++)
#pragma unroll
        for (int r = 0; r < 4; r++) {
          const int kcol = kb * 64 + nt * 16 + quad * 4 + r;
          sv[nt][r] = (kcol <= qrow_g) ? sv[nt][r] * SCL : -__builtin_inff();
          lmx = fmaxf(lmx, sv[nt][r]);
        }
    }
    lmx = fmaxf(lmx, __shfl_xor(lmx, 16, 64));
    lmx = fmaxf(lmx, __shfl_xor(lmx, 32, 64));
    const float mnew = fmaxf(mrow, lmx);
    const float alpha = __builtin_amdgcn_exp2f(mrow - mnew);
    mrow = mnew;
    // ---- exp2 + sum + packed P write (padded stride, b64) ----
    float psum = 0.f;
#pragma unroll
    for (int nt = 0; nt < 4; nt++) {
#pragma unroll
      for (int r = 0; r < 4; r++) {
        float p = __builtin_amdgcn_exp2f(sv[nt][r] - mnew);
        sv[nt][r] = p;
        psum += p;
      }
      uint2 u;
      u.x = pack_bf2(sv[nt][1], sv[nt][0]);
      u.y = pack_bf2(sv[nt][3], sv[nt][2]);
      *(uint2*)&Pw[l15 * 72 + nt * 16 + quad * 4] = u;
    }
    psum += __shfl_xor(psum, 16, 64);
    psum += __shfl_xor(psum, 32, 64);
    lrow = lrow * alpha + psum;
    // ---- rescale accO (alpha broadcast: lane j<16 holds row j's alpha) ----
    float al[4];
#pragma unroll
    for (int r = 0; r < 4; r++) al[r] = __shfl(alpha, quad * 4 + r, 64);
#pragma unroll
    for (int dt = 0; dt < 8; dt++)
#pragma unroll
      for (int r = 0; r < 4; r++) accO[dt][r] *= al[r];
    // drain this wave's P writes before fragment reads (per-wave buffer)
    asm volatile("s_waitcnt lgkmcnt(0)" ::: "memory");
    // ---- PV: P(16x64) @ V^T panels ----
    bf16x8 pf[2];
#pragma unroll
    for (int ksb = 0; ksb < 2; ksb++)
      pf[ksb] = *(const bf16x8*)&Pw[l15 * 72 + ksb * 32 + quad * 8];
#pragma unroll
    for (int dt = 0; dt < 8; dt++) {
#pragma unroll
      for (int ksb = 0; ksb < 2; ksb++) {
        bf16x8 vf = *(const bf16x8*)&Vs[ksb * 4096 + (dt * 16 + l15) * 32 + quad * 8];
        accO[dt] = __builtin_amdgcn_mfma_f32_16x16x32_bf16(pf[ksb], vf, accO[dt], 0, 0, 0);
      }
    }
  }
  // ---- epilogue: normalize by l (broadcast like alpha) and store ----
  const float linv = 1.f / lrow;
  float li[4];
#pragma unroll
  for (int r = 0; r < 4; r++) li[r] = __shfl(linv, quad * 4 + r, 64);
#pragma unroll
  for (int r = 0; r < 4; r++) {
    const long srow = (long)qb * 64 + wave * 16 + quad * 4 + r;
#pragma unroll
    for (int dt = 0; dt < 8; dt++)
      o_bf[srow * HIDN + h * HDIM + dt * 16 + l15] = f2bf(accO[dt][r] * li[r]);
  }
}

// ---------------- workspace layout ----------------
static constexpr size_t SZ_WQKVT = (size_t)NQKV * HIDN * 2;
static constexpr size_t SZ_WOT = (size_t)HIDN * HIDN * 2;
static constexpr size_t SZ_WBIG = (size_t)INTER * HIDN * 2;
static constexpr size_t OFF_WQKVT = 0;
static constexpr size_t OFF_WOT = OFF_WQKVT + SZ_WQKVT;
static constexpr size_t OFF_WGU = OFF_WOT + SZ_WOT;        // Wgu^T interleaved [2*INTER][HIDN]
static constexpr size_t OFF_WDOWNT = OFF_WGU + 2 * SZ_WBIG;
static constexpr size_t OFF_BIAS = OFF_WDOWNT + SZ_WBIG;
static constexpr size_t OFF_MASK = OFF_BIAS + 3072 * 4 + 4096;
static constexpr size_t OFF_QM = OFF_MASK + 16 * 32 * 32 + 4096;
static constexpr size_t OFF_KM = OFF_QM + (size_t)32 * 16 * 128 * 4;
static constexpr size_t OFF_QG = OFF_KM + (size_t)32 * 4 * 128 * 4;
static constexpr size_t OFF_KG = OFF_QG + (size_t)32 * 16 * 128 * 4;
static constexpr size_t OFF_H2 = OFF_KG + (size_t)32 * 4 * 128 * 4;
static constexpr size_t OFF_H3 = OFF_H2 + (size_t)S_LEN * HIDN * 4;
static constexpr size_t OFF_REGA = OFF_H3 + (size_t)S_LEN * HIDN * 2;
//   REGA timeline: h_bf | q_bf | k_bf | v_t | o_bf  ->  p0 for Wdown split-K
static constexpr size_t RA_HBF = 0;
static constexpr size_t RA_QBF = RA_HBF + (size_t)S_LEN * HIDN * 2;
static constexpr size_t RA_KBF = RA_QBF + (size_t)HQ * S_LEN * HDIM * 2;
static constexpr size_t RA_VT = RA_KBF + (size_t)HKV * S_LEN * HDIM * 2;
static constexpr size_t RA_OBF = RA_VT + (size_t)HKV * HDIM * S_LEN * 2;
static constexpr size_t SZ_REGA = RA_OBF + (size_t)S_LEN * HIDN * 2;
static constexpr size_t OFF_REGB = OFF_REGA + SZ_REGA;
//   REGB timeline: qkv_f32 (25.2MB) -> Wo split-K p0 (16.8MB)
//                  -> act_bf (23.1MB, direct from MODE-5 GEMM). All sequential.
static constexpr size_t SZ_REGB = (size_t)S_LEN * NQKV * 4;
static constexpr size_t TOTAL_WS = OFF_REGB + SZ_REGB;

extern "C" void kernel_launch(void* const* d_in, const int* in_sizes, int n_in,
                              void* d_out, int out_size, void* d_ws, size_t ws_size,
                              hipStream_t stream) {
  const float* hidden = (const float*)d_in[0];
  const float* cosb = (const float*)d_in[1];
  const float* sinb = (const float*)d_in[2];
  const float* ln1 = (const float*)d_in[3];
  const float* ln2 = (const float*)d_in[4];
  const float* Wq = (const float*)d_in[5];
  const float* bq = (const float*)d_in[6];
  const float* Wk = (const float*)d_in[7];
  const float* bk = (const float*)d_in[8];
  const float* Wv = (const float*)d_in[9];
  const float* bv = (const float*)d_in[10];
  const float* Wo = (const float*)d_in[11];
  const float* gWq = (const float*)d_in[12];
  const float* gWk = (const float*)d_in[13];
  const float* Wgate = (const float*)d_in[14];
  const float* Wup = (const float*)d_in[15];
  const float* Wdown = (const float*)d_in[16];

  if (ws_size < TOTAL_WS) return;  // workspace too small; fail visibly

  char* ws = (char*)d_ws;
  short* WqkvT = (short*)(ws + OFF_WQKVT);
  short* WoT = (short*)(ws + OFF_WOT);
  short* Wgu = (short*)(ws + OFF_WGU);        // interleaved [2*INTER][HIDN]
  short* WdownT = (short*)(ws + OFF_WDOWNT);
  float* biasqkv = (float*)(ws + OFF_BIAS);
  unsigned char* maskb = (unsigned char*)(ws + OFF_MASK);
  float* qm = (float*)(ws + OFF_QM);
  float* km = (float*)(ws + OFF_KM);
  float* qg = (float*)(ws + OFF_QG);
  float* kg = (float*)(ws + OFF_KG);
  float* h2 = (float*)(ws + OFF_H2);
  short* h3_bf = (short*)(ws + OFF_H3);
  short* h_bf = (short*)(ws + OFF_REGA + RA_HBF);
  short* q_bf = (short*)(ws + OFF_REGA + RA_QBF);
  short* k_bf = (short*)(ws + OFF_REGA + RA_KBF);
  short* v_t = (short*)(ws + OFF_REGA + RA_VT);
  short* o_bf = (short*)(ws + OFF_REGA + RA_OBF);
  float* p0b = (float*)(ws + OFF_REGA);       // Wdown split-K p0 (REGA dead by then)
  float* qkv_f = (float*)(ws + OFF_REGB);
  float* p0a = (float*)(ws + OFF_REGB);       // Wo split-K p0 (qkv_f dead by then)
  short* act_bf = (short*)(ws + OFF_REGB);    // MODE-5 output (p0a dead by then)
  float* outp = (float*)d_out;

  dim3 tb(32, 8);
  // weight transposes (fp32 -> bf16, N x K)
  k_transpose_cast<<<dim3(64, 64), tb, 0, stream>>>(Wq, WqkvT, HIDN, 2048);
  k_transpose_cast<<<dim3(16, 64), tb, 0, stream>>>(Wk, WqkvT + (size_t)2048 * HIDN, HIDN, 512);
  k_transpose_cast<<<dim3(16, 64), tb, 0, stream>>>(Wv, WqkvT + (size_t)2560 * HIDN, HIDN, 512);
  k_transpose_cast<<<dim3(64, 64), tb, 0, stream>>>(Wo, WoT, HIDN, HIDN);
  // gate/up -> interleaved Wgu^T (16-row groups alternate gate/up)
  k_transpose_cast_ilv<<<dim3(176, 64), tb, 0, stream>>>(Wgate, Wgu, HIDN, INTER, 0);
  k_transpose_cast_ilv<<<dim3(176, 64), tb, 0, stream>>>(Wup, Wgu, HIDN, INTER, 1);
  k_transpose_cast<<<dim3(64, 176), tb, 0, stream>>>(Wdown, WdownT, INTER, HIDN);
  k_bias_concat<<<12, 256, 0, stream>>>(bq, bk, bv, biasqkv);

  // h = RMS(hidden, ln1) -> bf16
  k_rms<<<S_LEN, 256, 0, stream>>>(hidden, ln1, h_bf);
  // qkv = h @ [Wq|Wk|Wv] + bias  (fp32)  [BN=64: 768 blocks, 3/CU]
  k_gemm<0, 64><<<dim3(NQKV / 64, S_LEN / 128), 256, 0, stream>>>(
      h_bf, WqkvT, qkv_f, nullptr, nullptr, biasqkv, nullptr, S_LEN, NQKV, HIDN, HIDN);
  // gate path (pre-RoPE q,k)
  k_blockmean<<<320, 256, 0, stream>>>(qkv_f, qm, km);
  k_gateproj<<<640, 128, 0, stream>>>(qm, km, gWq, gWk, qg, kg);
  k_gatemask<<<dim3(32, 16), 64, 0, stream>>>(qg, kg, maskb);
  // RoPE + layout change
  k_rope<<<10240, 256, 0, stream>>>(qkv_f, cosb, sinb, q_bf, k_bf);
  k_vcast_t<<<dim3(4, 64, 4), tb, 0, stream>>>(qkv_f, v_t);
  // attention
  k_attn<<<dim3(32, 16), 256, 0, stream>>>(q_bf, k_bf, v_t, maskb, o_bf);
  // Wo partials = o @ Wo  (split-K x2: 1024 blocks, 4/CU; reduce fused into rms)
  k_gemm<4, 64><<<dim3(HIDN / 64, S_LEN / 128, 2), 256, 0, stream>>>(
      o_bf, WoT, p0a, h2, nullptr, nullptr, nullptr, S_LEN, HIDN, HIDN, HIDN / 2);
  // h2 = p0 + p1 + hidden ; h3 = RMS(h2, ln2) -> bf16
  k_rms_fin<<<S_LEN, 256, 0, stream>>>(p0a, hidden, ln2, h2, h3_bf);
  // act = silu(h3@Wgate) * (h3@Wup) in ONE GEMM (interleaved B, fused epilogue)
  k_gemm<5, 128><<<dim3(2 * INTER / 128, S_LEN / 128), 256, 0, stream>>>(
      h3_bf, Wgu, nullptr, nullptr, act_bf, nullptr, nullptr, S_LEN, 2 * INTER, HIDN, HIDN);
  // out partials = act @ Wdown  (split-K x2: 1024 blocks, 4/CU)
  k_gemm<4, 64><<<dim3(HIDN / 64, S_LEN / 128, 2), 256, 0, stream>>>(
      act_bf, WdownT, p0b, outp, nullptr, nullptr, nullptr, S_LEN, HIDN, INTER, INTER / 2);
  // out = out + p0 + h2
  k_finish<<<2048, 256, 0, stream>>>(p0b, h2, outp);
  (void)in_sizes; (void)n_in; (void)out_size;
}